// Round 4
// baseline (3612.653 us; speedup 1.0000x reference)
//
#include <hip/hip_runtime.h>
#include <math.h>

namespace {

constexpr int kB   = 8;
constexpr int kL   = 256;
constexpr int kTok = 2048;   // B*L
constexpr int kDM  = 384;
constexpr int kDI  = 768;
constexpr int kDS  = 16;
constexpr int kDTR = 24;
constexpr int kPROJ = 56;    // DTR + 2*DS
constexpr int kNL  = 12;

constexpr int kWIN  = 2 * kDI * kDM;   // 589824 in_proj weights/layer
constexpr int kWOUT = kDM * kDI;       // 294912
constexpr int kWX   = kPROJ * kDI;     // 43008
constexpr int kWTOT = kWIN + kWOUT + kWX;  // 927744

typedef float f32x4 __attribute__((ext_vector_type(4)));
typedef short short8 __attribute__((ext_vector_type(8)));

__device__ __forceinline__ float softplus_f(float x) {
  return (x > 20.f) ? x : log1pf(__expf(x));
}
__device__ __forceinline__ float silu_f(float x) {
  return x / (1.f + __expf(-x));
}
__device__ __forceinline__ unsigned short f2bf(float f) {
  union { float f; unsigned u; } v; v.f = f;
  unsigned r = v.u + 0x7FFFu + ((v.u >> 16) & 1u);
  return (unsigned short)(r >> 16);
}
__device__ __forceinline__ float bf2f(unsigned short u) {
  return __uint_as_float((unsigned)u << 16);
}

// Device-wide barrier: monotonic arrival counter (no reset -> no reuse race).
// seq_cst agent fences publish prior plain stores (L2 writeback) and
// invalidate stale L1/L2 lines across XCDs (G16).
__device__ __forceinline__ void gbar(unsigned* cnt, unsigned target) {
  __syncthreads();
  if (threadIdx.x == 0) {
    __builtin_amdgcn_fence(__ATOMIC_SEQ_CST, "agent");
    __hip_atomic_fetch_add(cnt, 1u, __ATOMIC_RELAXED, __HIP_MEMORY_SCOPE_AGENT);
    while (__hip_atomic_load(cnt, __ATOMIC_RELAXED, __HIP_MEMORY_SCOPE_AGENT) < target)
      __builtin_amdgcn_s_sleep(2);
    __builtin_amdgcn_fence(__ATOMIC_SEQ_CST, "agent");
  }
  __syncthreads();
}

// ------------- convert ALL layers' GEMM weights fp32 -> bf16 ---------------
// also zeroes pooled and the barrier counter (runs before mega each call)
__global__ __launch_bounds__(256) void convert_all_k(
    const float* __restrict__ w_in, const float* __restrict__ w_out,
    const float* __restrict__ w_x, unsigned short* __restrict__ dst,
    float* __restrict__ pooled_zero, unsigned* __restrict__ bar) {
  int layer = blockIdx.y;
  int tid = threadIdx.x;
  if (layer == 0 && blockIdx.x == 0) {
    for (int i = tid; i < kB * kDM; i += 256) pooled_zero[i] = 0.f;
    if (tid < 64) bar[tid] = 0u;
  }
  int i4 = (blockIdx.x * 256 + tid) * 4;
  if (i4 >= kWTOT) return;
  const float* src;
  int off;
  if (i4 < kWIN) { src = w_in + (size_t)layer * kWIN; off = i4; }
  else if (i4 < kWIN + kWOUT) { src = w_out + (size_t)layer * kWOUT; off = i4 - kWIN; }
  else { src = w_x + (size_t)layer * kWX; off = i4 - kWIN - kWOUT; }
  float4 v = *(const float4*)(src + off);
  unsigned short o[4] = {f2bf(v.x), f2bf(v.y), f2bf(v.z), f2bf(v.w)};
  *(uint2*)(dst + (size_t)layer * kWTOT + i4) = *(const uint2*)o;
}

// ------------- persistent mega-kernel: patch + 12 layers + LN-pool + head --
// Phases separated by device-wide barriers; one 48KB LDS arena reused.
__global__ __launch_bounds__(256, 2) void mega_k(
    const float* __restrict__ x, const float* __restrict__ patch_w,
    const float* __restrict__ patch_b, const float* __restrict__ pos,
    float* __restrict__ tok,
    const float* __restrict__ ln_g, const float* __restrict__ ln_b,
    const unsigned short* __restrict__ w_bf,
    const float* __restrict__ conv_w, const float* __restrict__ conv_b,
    const float* __restrict__ dtw_all, const float* __restrict__ dtb_all,
    const float* __restrict__ Alog_all, const float* __restrict__ Dsk_all,
    float* __restrict__ proj, unsigned short* __restrict__ xz_bf,
    unsigned short* __restrict__ uT_bf, unsigned short* __restrict__ sgT_bf,
    unsigned short* __restrict__ y_bf,
    const float* __restrict__ fn_g, const float* __restrict__ fn_b,
    const float* __restrict__ head_w, const float* __restrict__ head_b,
    float* __restrict__ pooled, float* __restrict__ out,
    unsigned* __restrict__ bar, int nblk) {
  __shared__ __align__(16) char smem[49152];
  const int tid = threadIdx.x;
  const int bid = blockIdx.x;
  const int wave = tid >> 6, lane = tid & 63;
  unsigned bt = 0;

  // ================= phase 0: patch embed GEMM =================
  {
    float (*As)[68] = (float(*)[68])smem;
    float (*Bs)[68] = (float(*)[68])(smem + 4352);
    for (int u = bid; u < 192; u += nblk) {
      __syncthreads();
      int bm = (u / 6) * 64;
      int bn = (u % 6) * 64;
      int lr = tid >> 2;
      int lk = (tid & 3) << 2;
      int tm = (tid >> 4) << 2;
      int tn = (tid & 15) << 2;
      float acc[4][4] = {};
      for (int k0 = 0; k0 < 256; k0 += 16) {
        {
          int token = bm + lr;
          int b = token >> 8, l = token & 255;
          int h = l >> 3, w = l & 7;
          int p = k0 >> 4;
          const float* ap = x + ((size_t)(b * 512) + h * 16 + p) * 128 + w * 16 + lk;
          float4 av = *(const float4*)ap;
          As[lk + 0][lr] = av.x; As[lk + 1][lr] = av.y;
          As[lk + 2][lr] = av.z; As[lk + 3][lr] = av.w;
        }
        {
          const float* bp = patch_w + (size_t)(bn + lr) * 256 + k0 + lk;
          float4 bv = *(const float4*)bp;
          Bs[lk + 0][lr] = bv.x; Bs[lk + 1][lr] = bv.y;
          Bs[lk + 2][lr] = bv.z; Bs[lk + 3][lr] = bv.w;
        }
        __syncthreads();
        #pragma unroll
        for (int k = 0; k < 16; ++k) {
          float4 a = *(const float4*)&As[k][tm];
          float4 b = *(const float4*)&Bs[k][tn];
          float av[4] = {a.x, a.y, a.z, a.w};
          float bv[4] = {b.x, b.y, b.z, b.w};
          #pragma unroll
          for (int i = 0; i < 4; ++i)
            #pragma unroll
            for (int j = 0; j < 4; ++j)
              acc[i][j] = fmaf(av[i], bv[j], acc[i][j]);
        }
        __syncthreads();
      }
      #pragma unroll
      for (int i = 0; i < 4; ++i) {
        int row = bm + tm + i;
        #pragma unroll
        for (int j = 0; j < 4; ++j) {
          int col = bn + tn + j;
          tok[(size_t)row * kDM + col] =
              acc[i][j] + patch_b[col] + pos[(size_t)(row & 255) * kDM + col];
        }
      }
    }
  }
  gbar(bar, bt += (unsigned)nblk);

  for (int layer = 0; layer < kNL; ++layer) {
    const unsigned short* wl = w_bf + (size_t)layer * kWTOT;

    // ================= phase A: in_proj + fused LN (64x96 tiles) ===========
    {
      // zero proj for phase-B split-K atomics
      for (int i = bid * 256 + tid; i < kTok * kPROJ; i += nblk * 256)
        proj[i] = 0.f;
      float* sg_ = (float*)smem;                       // 384 f
      float* sb_ = (float*)(smem + 1536);              // 384 f
      float* smean = (float*)(smem + 3072);            // 64 f
      float* srstd = (float*)(smem + 3328);            // 64 f
      auto As = (unsigned short (*)[64][8])(smem + 3584);   // 4 KB
      auto Bs = (unsigned short (*)[96][8])(smem + 7680);   // 6 KB
      const float* g = ln_g + (size_t)layer * kDM;
      const float* bbp = ln_b + (size_t)layer * kDM;
      for (int u = bid; u < 512; u += nblk) {
        __syncthreads();
        int bm = (u >> 4) * 64;
        int bn = (u & 15) * 96;
        for (int i = tid; i < kDM; i += 256) { sg_[i] = g[i]; sb_[i] = bbp[i]; }
        {
          int r = tid >> 2, quarter = tid & 3;
          const float* rp = tok + (size_t)(bm + r) * kDM + quarter * 96;
          float s = 0.f, s2 = 0.f;
          #pragma unroll
          for (int q = 0; q < 24; ++q) {
            float4 v = ((const float4*)rp)[q];
            s  += v.x + v.y + v.z + v.w;
            s2 += v.x * v.x + v.y * v.y + v.z * v.z + v.w * v.w;
          }
          s  += __shfl_xor(s, 1);  s2 += __shfl_xor(s2, 1);
          s  += __shfl_xor(s, 2);  s2 += __shfl_xor(s2, 2);
          if (quarter == 0) {
            float mean = s * (1.f / 384.f);
            float var  = s2 * (1.f / 384.f) - mean * mean;
            smean[r] = mean;
            srstd[r] = rsqrtf(var + 1e-5f);
          }
        }
        __syncthreads();
        int lm = lane & 15, lq = lane >> 4;
        int wm = (wave & 1) * 32, wn = (wave >> 1) * 48;
        int ar = tid & 63, aq = tid >> 6;
        int r0 = tid >> 2, q0 = tid & 3;            // B slot tid
        int r1 = (tid + 256) >> 2;                  // B slot tid+256 (tid<128)
        f32x4 acc[2][3] = {};
        for (int k0 = 0; k0 < kDM; k0 += 32) {
          unsigned short av[8];
          {
            float mean = smean[ar], rstd = srstd[ar];
            const float* ap = tok + (size_t)(bm + ar) * kDM + k0 + aq * 8;
            float4 v0 = ((const float4*)ap)[0];
            float4 v1 = ((const float4*)ap)[1];
            float vv[8] = {v0.x, v0.y, v0.z, v0.w, v1.x, v1.y, v1.z, v1.w};
            #pragma unroll
            for (int j = 0; j < 8; ++j) {
              int k = k0 + aq * 8 + j;
              av[j] = f2bf((vv[j] - mean) * rstd * sg_[k] + sb_[k]);
            }
          }
          uint4 bv0 = *(const uint4*)(wl + (size_t)(bn + r0) * kDM + k0 + q0 * 8);
          uint4 bv1 = make_uint4(0u, 0u, 0u, 0u);
          if (tid < 128)
            bv1 = *(const uint4*)(wl + (size_t)(bn + r1) * kDM + k0 + q0 * 8);
          __syncthreads();
          *(uint4*)&As[aq][ar][0] = *(const uint4*)av;
          *(uint4*)&Bs[q0][r0][0] = bv0;
          if (tid < 128) *(uint4*)&Bs[q0][r1][0] = bv1;
          __syncthreads();
          short8 bfrag[3];
          #pragma unroll
          for (int ni = 0; ni < 3; ++ni)
            bfrag[ni] = *(const short8*)&Bs[lq][wn + ni * 16 + lm][0];
          #pragma unroll
          for (int mi = 0; mi < 2; ++mi) {
            short8 afrag = *(const short8*)&As[lq][wm + mi * 16 + lm][0];
            #pragma unroll
            for (int ni = 0; ni < 3; ++ni)
              acc[mi][ni] = __builtin_amdgcn_mfma_f32_16x16x32_bf16(
                  afrag, bfrag[ni], acc[mi][ni], 0, 0, 0);
          }
        }
        #pragma unroll
        for (int mi = 0; mi < 2; ++mi) {
          #pragma unroll
          for (int ni = 0; ni < 3; ++ni) {
            int grow0 = bm + wm + mi * 16 + lq * 4;
            int gcol = bn + wn + ni * 16 + lm;
            #pragma unroll
            for (int r = 0; r < 4; ++r)
              xz_bf[(size_t)(grow0 + r) * (2 * kDI) + gcol] = f2bf(acc[mi][ni][r]);
          }
        }
      }
    }
    gbar(bar, bt += (unsigned)nblk);

    // ================= phase B: x_proj + conv + SiLU + z-gate ==============
    {
      auto As = (unsigned short (*)[64][8])smem;            // 4 KB
      auto Bs = (unsigned short (*)[64][8])(smem + 4096);   // 4 KB
      auto scw = (float (*)[4])(smem + 8192);               // 2 KB
      float* scb = (float*)(smem + 10240);                  // 0.5 KB
      const float* cw = conv_w + (size_t)layer * kDI * 4;
      const float* cb = conv_b + (size_t)layer * kDI;
      const unsigned short* Bw = wl + kWIN + kWOUT;
      for (int u = bid; u < 192; u += nblk) {
        __syncthreads();
        int bm = (u & 31) * 64;
        int kbase = (u >> 5) * 128;
        int lm = lane & 15, lq = lane >> 4;
        int wm = wave * 16;
        f32x4 acc[4] = {};
        if (tid < 128) {
          *(float4*)&scw[tid][0] = *(const float4*)(cw + (size_t)(kbase + tid) * 4);
          scb[tid] = cb[kbase + tid];
        }
        __syncthreads();
        int ar = tid & 63;
        int aq = tid >> 6;
        int t = bm + ar;
        int b = t >> 8, l = t & 255;
        for (int kt = 0; kt < 4; ++kt) {
          int k0 = kbase + kt * 32;
          int dloc = kt * 32 + aq * 8;
          int dg = kbase + dloc;
          unsigned short av[8];
          {
            float vals[4][8];
            #pragma unroll
            for (int q = 0; q < 4; ++q) {
              if (l - 3 + q >= 0) {
                uint4 r = *(const uint4*)(xz_bf + (size_t)(t - 3 + q) * (2 * kDI) + dg);
                const unsigned short* rs = (const unsigned short*)&r;
                #pragma unroll
                for (int j = 0; j < 8; ++j) vals[q][j] = bf2f(rs[j]);
              } else {
                #pragma unroll
                for (int j = 0; j < 8; ++j) vals[q][j] = 0.f;
              }
            }
            uint4 zr = *(const uint4*)(xz_bf + (size_t)t * (2 * kDI) + kDI + dg);
            const unsigned short* zs = (const unsigned short*)&zr;
            #pragma unroll
            for (int j = 0; j < 8; ++j) {
              float a = scb[dloc + j];
              a = fmaf(vals[0][j], scw[dloc + j][0], a);
              a = fmaf(vals[1][j], scw[dloc + j][1], a);
              a = fmaf(vals[2][j], scw[dloc + j][2], a);
              a = fmaf(vals[3][j], scw[dloc + j][3], a);
              unsigned short ub = f2bf(silu_f(a));
              av[j] = ub;
              size_t rbase = ((size_t)b * kDI + dg + j) * kL + l;
              uT_bf[rbase] = ub;
              sgT_bf[rbase] = f2bf(silu_f(bf2f(zs[j])));
            }
          }
          int br = tid & 63, bq = tid >> 6;
          uint4 b0;
          if (br < kPROJ)
            b0 = *(const uint4*)(Bw + (size_t)br * kDI + k0 + bq * 8);
          else
            b0 = make_uint4(0u, 0u, 0u, 0u);
          __syncthreads();
          *(uint4*)&As[aq][ar][0] = *(const uint4*)av;
          *(uint4*)&Bs[bq][br][0] = b0;
          __syncthreads();
          short8 afrag = *(const short8*)&As[lq][wm + lm][0];
          #pragma unroll
          for (int ni = 0; ni < 4; ++ni) {
            short8 bfrag = *(const short8*)&Bs[lq][ni * 16 + lm][0];
            acc[ni] = __builtin_amdgcn_mfma_f32_16x16x32_bf16(
                afrag, bfrag, acc[ni], 0, 0, 0);
          }
        }
        #pragma unroll
        for (int ni = 0; ni < 4; ++ni) {
          int grow0 = bm + wm + lq * 4;
          int gcol = ni * 16 + lm;
          if (gcol < kPROJ) {
            #pragma unroll
            for (int r = 0; r < 4; ++r)
              atomicAdd(&proj[(size_t)(grow0 + r) * kPROJ + gcol], acc[ni][r]);
          }
        }
      }
    }
    gbar(bar, bt += (unsigned)nblk);

    // ================= phase C: scan (LDS-staged proj panel) ===============
    {
      float (*sproj)[33] = (float(*)[33])smem;                  // 33792 B
      auto sdt = (float (*)[16][5])(smem + 33792);              // 5120 B
      auto sh  = (float (*)[16][5])(smem + 38912);              // 5120 B
      auto sca = (float (*)[16][5])(smem + 44032);              // 5120 B
      const float* dtw = dtw_all + (size_t)layer * kDI * kDTR;
      const float* dtb = dtb_all + (size_t)layer * kDI;
      const float* Alog = Alog_all + (size_t)layer * kDI * kDS;
      const float* Dskp = Dsk_all + (size_t)layer * kDI;
      int dsub = tid & 3;
      int nq = (tid >> 2) & 3;
      int c = tid >> 4;
      for (int u = bid; u < 1536; u += nblk) {
        __syncthreads();   // protect sproj/sh/sca from previous unit readers
        int d0 = (u % 192) * 4;
        int b = u / 192;
        int d = d0 + dsub;
        const float* pr0 = proj + (size_t)(b * kL) * kPROJ;
        // stage A: proj cols 0..23 -> sproj[tok][0..23]
        {
          const float* rp = pr0 + (size_t)tid * kPROJ;
          #pragma unroll
          for (int q = 0; q < 6; ++q) {
            float4 v = ((const float4*)rp)[q];
            sproj[tid][q * 4 + 0] = v.x;
            sproj[tid][q * 4 + 1] = v.y;
            sproj[tid][q * 4 + 2] = v.z;
            sproj[tid][q * 4 + 3] = v.w;
          }
        }
        float Av2[4];
        {
          const float kLog2e = 1.44269504088896340736f;
          float4 v = *(const float4*)(Alog + (size_t)d * kDS + nq * 4);
          Av2[0] = -__expf(v.x) * kLog2e;
          Av2[1] = -__expf(v.y) * kLog2e;
          Av2[2] = -__expf(v.z) * kLog2e;
          Av2[3] = -__expf(v.w) * kLog2e;
        }
        float bdt = dtb[d];
        float Dv = Dskp[d];
        float wdt[24];
        {
          const float* wp = dtw + (size_t)d * kDTR;
          #pragma unroll
          for (int q = 0; q < 6; ++q) {
            float4 v = ((const float4*)wp)[q];
            wdt[q * 4 + 0] = v.x; wdt[q * 4 + 1] = v.y;
            wdt[q * 4 + 2] = v.z; wdt[q * 4 + 3] = v.w;
          }
        }
        union { uint4 v[2]; unsigned short s[16]; } uu;
        {
          const unsigned short* up = uT_bf + ((size_t)b * kDI + d) * kL + c * 16;
          uu.v[0] = ((const uint4*)up)[0];
          uu.v[1] = ((const uint4*)up)[1];
        }
        __syncthreads();   // stage A visible
        #pragma unroll
        for (int i = 0; i < 4; ++i) {
          int tk = c * 16 + nq * 4 + i;
          float acc = bdt;
          #pragma unroll
          for (int r = 0; r < 24; ++r) acc = fmaf(sproj[tk][r], wdt[r], acc);
          sdt[c][nq * 4 + i][dsub] = softplus_f(acc);
        }
        __syncthreads();   // dt reads done; sdt written
        // stage B: proj cols 24..55 -> sproj[tok][0..31]
        {
          const float* rp = pr0 + (size_t)tid * kPROJ + 24;
          #pragma unroll
          for (int q = 0; q < 8; ++q) {
            float4 v = ((const float4*)rp)[q];
            sproj[tid][q * 4 + 0] = v.x;
            sproj[tid][q * 4 + 1] = v.y;
            sproj[tid][q * 4 + 2] = v.z;
            sproj[tid][q * 4 + 3] = v.w;
          }
        }
        __syncthreads();   // stage B visible
        // pass 1
        float h[4] = {};
        float S = 0.f;
        #pragma unroll
        for (int i = 0; i < 16; ++i) {
          int tk = c * 16 + i;
          float dl = sdt[c][i][dsub];
          float du = dl * bf2f(uu.s[i]);
          S += dl;
          #pragma unroll
          for (int n = 0; n < 4; ++n) {
            float a = exp2f(dl * Av2[n]);
            h[n] = fmaf(a, h[n], du * sproj[tk][nq * 4 + n]);
          }
        }
        {
          int nrow = nq * 4;
          #pragma unroll
          for (int n = 0; n < 4; ++n) {
            sh[c][nrow + n][dsub] = h[n];
            sca[c][nrow + n][dsub] = exp2f(S * Av2[n]);
          }
        }
        __syncthreads();
        // chunk-prefix combine
        float h0[4] = {};
        {
          int nrow = nq * 4;
          for (int j = 0; j < c; ++j) {
            #pragma unroll
            for (int n = 0; n < 4; ++n)
              h0[n] = fmaf(sca[j][nrow + n][dsub], h0[n], sh[j][nrow + n][dsub]);
          }
        }
        union { uint4 v[2]; unsigned short s[16]; } zz;
        zz.v[0] = make_uint4(0u, 0u, 0u, 0u);
        zz.v[1] = make_uint4(0u, 0u, 0u, 0u);
        if (nq == 0) {
          const unsigned short* sp = sgT_bf + ((size_t)b * kDI + d) * kL + c * 16;
          zz.v[0] = ((const uint4*)sp)[0];
          zz.v[1] = ((const uint4*)sp)[1];
        }
        // pass 2
        unsigned short* yp = y_bf + (size_t)(b * kL + c * 16) * kDI + d;
        #pragma unroll
        for (int i = 0; i < 16; ++i) {
          int tk = c * 16 + i;
          float dl = sdt[c][i][dsub];
          float uv = bf2f(uu.s[i]);
          float du = dl * uv;
          float yv = 0.f;
          #pragma unroll
          for (int n = 0; n < 4; ++n) {
            float a = exp2f(dl * Av2[n]);
            h0[n] = fmaf(a, h0[n], du * sproj[tk][nq * 4 + n]);
            yv = fmaf(h0[n], sproj[tk][16 + nq * 4 + n], yv);
          }
          yv += __shfl_xor(yv, 4);
          yv += __shfl_xor(yv, 8);
          if (nq == 0) yp[(size_t)i * kDI] = f2bf((yv + uv * Dv) * bf2f(zz.s[i]));
        }
      }
    }
    gbar(bar, bt += (unsigned)nblk);

    // ================= phase D: out_proj GEMM (64x64, split-K=4) ===========
    {
      auto As = (unsigned short (*)[64][8])smem;            // 4 KB
      auto Bs = (unsigned short (*)[64][8])(smem + 4096);   // 4 KB
      const unsigned short* Bw = wl + kWIN;
      for (int u = bid; u < 768; u += nblk) {
        __syncthreads();
        int bn = (u % 6) * 64;
        int bm = ((u / 6) & 31) * 64;
        int k_begin = (u / 192) * 192;
        int lm = lane & 15, lq = lane >> 4;
        int wm = (wave & 1) * 32, wn = (wave >> 1) * 32;
        f32x4 acc[2][2] = {};
        for (int kt = 0; kt < 192; kt += 32) {
          int k0 = k_begin + kt;
          int ar = tid & 63, aq = tid >> 6;
          uint4 a0 = *(const uint4*)(y_bf + (size_t)(bm + ar) * kDI + k0 + aq * 8);
          uint4 b0 = *(const uint4*)(Bw + (size_t)(bn + ar) * kDI + k0 + aq * 8);
          __syncthreads();
          *(uint4*)&As[aq][ar][0] = a0;
          *(uint4*)&Bs[aq][ar][0] = b0;
          __syncthreads();
          short8 bfrag[2];
          #pragma unroll
          for (int ni = 0; ni < 2; ++ni)
            bfrag[ni] = *(const short8*)&Bs[lq][wn + ni * 16 + lm][0];
          #pragma unroll
          for (int mi = 0; mi < 2; ++mi) {
            short8 afrag = *(const short8*)&As[lq][wm + mi * 16 + lm][0];
            #pragma unroll
            for (int ni = 0; ni < 2; ++ni)
              acc[mi][ni] = __builtin_amdgcn_mfma_f32_16x16x32_bf16(
                  afrag, bfrag[ni], acc[mi][ni], 0, 0, 0);
          }
        }
        #pragma unroll
        for (int mi = 0; mi < 2; ++mi) {
          #pragma unroll
          for (int ni = 0; ni < 2; ++ni) {
            int grow0 = bm + wm + mi * 16 + lq * 4;
            int gcol = bn + wn + ni * 16 + lm;
            #pragma unroll
            for (int r = 0; r < 4; ++r)
              atomicAdd(&tok[(size_t)(grow0 + r) * kDM + gcol], acc[mi][ni][r]);
          }
        }
      }
    }
    gbar(bar, bt += (unsigned)nblk);
  }

  // ================= final LN + mean-pool (one wave per token) =============
  {
    for (int t = bid * 4 + wave; t < kTok; t += nblk * 4) {
      float v[6];
      float s = 0.f, s2 = 0.f;
      #pragma unroll
      for (int j = 0; j < 6; ++j) {
        int d = lane + j * 64;
        v[j] = tok[(size_t)t * kDM + d];
        s += v[j];
        s2 += v[j] * v[j];
      }
      #pragma unroll
      for (int m = 32; m >= 1; m >>= 1) {
        s  += __shfl_xor(s, m);
        s2 += __shfl_xor(s2, m);
      }
      float mean = s * (1.f / 384.f);
      float var  = s2 * (1.f / 384.f) - mean * mean;
      float r = rsqrtf(var + 1e-5f);
      #pragma unroll
      for (int j = 0; j < 6; ++j) {
        int d = lane + j * 64;
        float o = (v[j] - mean) * r * fn_g[d] + fn_b[d];
        atomicAdd(&pooled[(size_t)(t >> 8) * kDM + d], o * (1.f / 256.f));
      }
    }
  }
  gbar(bar, bt += (unsigned)nblk);

  // ================= head =================
  for (int u = bid; u < kB * 4; u += nblk) {
    if (wave == 0) {
      int b = u >> 2, c = u & 3;
      float acc = 0.f;
      #pragma unroll
      for (int j = 0; j < 6; ++j) {
        int d = lane + j * 64;
        acc = fmaf(pooled[(size_t)b * kDM + d], head_w[(size_t)c * kDM + d], acc);
      }
      #pragma unroll
      for (int m = 32; m >= 1; m >>= 1) acc += __shfl_xor(acc, m);
      if (lane == 0) out[b * 4 + c] = acc + head_b[c];
    }
  }
}

}  // namespace

extern "C" void kernel_launch(void* const* d_in, const int* in_sizes, int n_in,
                              void* d_out, int out_size, void* d_ws, size_t ws_size,
                              hipStream_t stream) {
  (void)in_sizes; (void)n_in; (void)out_size; (void)ws_size;
  const float* x        = (const float*)d_in[0];
  const float* patch_w  = (const float*)d_in[1];
  const float* patch_b  = (const float*)d_in[2];
  const float* pos      = (const float*)d_in[3];
  const float* ln_g     = (const float*)d_in[4];
  const float* ln_b     = (const float*)d_in[5];
  const float* in_w     = (const float*)d_in[6];
  const float* conv_w   = (const float*)d_in[7];
  const float* conv_b   = (const float*)d_in[8];
  const float* xproj_w  = (const float*)d_in[9];
  const float* dtproj_w = (const float*)d_in[10];
  const float* dtproj_b = (const float*)d_in[11];
  const float* A_log    = (const float*)d_in[12];
  const float* Dskip    = (const float*)d_in[13];
  const float* out_w    = (const float*)d_in[14];
  const float* fn_g     = (const float*)d_in[15];
  const float* fn_b     = (const float*)d_in[16];
  const float* head_w   = (const float*)d_in[17];
  const float* head_b   = (const float*)d_in[18];
  float* out = (float*)d_out;

  // persistent-grid size: 2 blocks/CU, capped at 512 (LDS-bound residency)
  static int nblk = 0;
  if (nblk == 0) {
    hipDeviceProp_t prop;
    hipGetDeviceProperties(&prop, 0);
    int b2 = prop.multiProcessorCount * 2;
    nblk = b2 < 512 ? b2 : 512;
    if (nblk < 1) nblk = 1;
  }

  float* ws = (float*)d_ws;
  unsigned* bar = (unsigned*)ws; ws += 64;    // barrier counter (256 B)
  float* tok    = ws; ws += kTok * kDM;       // fp32 residual
  float* proj   = ws; ws += kTok * kPROJ;     // [t][56] row-major
  float* pooled = ws; ws += kB * kDM;
  unsigned short* xz_bf  = (unsigned short*)ws; ws += kTok * 2 * kDI / 2;
  unsigned short* uT_bf  = (unsigned short*)ws; ws += kTok * kDI / 2;
  unsigned short* sgT_bf = (unsigned short*)ws; ws += kTok * kDI / 2;
  unsigned short* y_bf   = (unsigned short*)ws; ws += kTok * kDI / 2;
  unsigned short* w_bf   = (unsigned short*)ws; ws += (size_t)kNL * kWTOT / 2;

  // weight cast + pooled/barrier zero-init (runs before mega on the stream)
  convert_all_k<<<dim3(kWTOT / 4 / 256, kNL), 256, 0, stream>>>(
      in_w, out_w, xproj_w, w_bf, pooled, bar);

  // everything else: one persistent kernel (patch + 12 layers + LN-pool + head)
  mega_k<<<nblk, 256, 0, stream>>>(
      x, patch_w, patch_b, pos, tok, ln_g, ln_b, w_bf, conv_w, conv_b,
      dtproj_w, dtproj_b, A_log, Dskip, proj, xz_bf, uT_bf, sgT_bf, y_bf,
      fn_g, fn_b, head_w, head_b, pooled, out, bar, nblk);
}

// Round 5
// 1248.383 us; speedup vs baseline: 2.8939x; 2.8939x over previous
//
#include <hip/hip_runtime.h>
#include <math.h>

namespace {

constexpr int kB   = 8;
constexpr int kL   = 256;
constexpr int kTok = 2048;   // B*L
constexpr int kDM  = 384;
constexpr int kDI  = 768;
constexpr int kDS  = 16;
constexpr int kDTR = 24;
constexpr int kPROJ = 56;    // DTR + 2*DS
constexpr int kNL  = 12;

constexpr int kWIN  = 2 * kDI * kDM;   // 589824 in_proj weights/layer
constexpr int kWOUT = kDM * kDI;       // 294912
constexpr int kWX   = kPROJ * kDI;     // 43008
constexpr int kWTOT = kWIN + kWOUT + kWX;  // 927744

typedef float f32x4 __attribute__((ext_vector_type(4)));
typedef short short8 __attribute__((ext_vector_type(8)));

__device__ __forceinline__ float softplus_f(float x) {
  return (x > 20.f) ? x : log1pf(__expf(x));
}
__device__ __forceinline__ float silu_f(float x) {
  return x / (1.f + __expf(-x));
}
__device__ __forceinline__ unsigned short f2bf(float f) {
  union { float f; unsigned u; } v; v.f = f;
  unsigned r = v.u + 0x7FFFu + ((v.u >> 16) & 1u);
  return (unsigned short)(r >> 16);
}
__device__ __forceinline__ float bf2f(unsigned short u) {
  return __uint_as_float((unsigned)u << 16);
}

// ------------- patch embed GEMM: tok = im2col(x)·patch_w^T + b + pos -------
__global__ __launch_bounds__(256) void patch_gemm_k(
    const float* __restrict__ x, const float* __restrict__ Bw,
    const float* __restrict__ bias, const float* __restrict__ pos,
    float* __restrict__ C) {
  __shared__ float As[16][68];
  __shared__ float Bs[16][68];
  int tid = threadIdx.x;
  int bm = blockIdx.y * 64;
  int bn = blockIdx.x * 64;
  int lr = tid >> 2;
  int lk = (tid & 3) << 2;
  int tm = (tid >> 4) << 2;
  int tn = (tid & 15) << 2;
  float acc[4][4] = {};
  for (int k0 = 0; k0 < 256; k0 += 16) {
    {
      int token = bm + lr;
      int b = token >> 8, l = token & 255;
      int h = l >> 3, w = l & 7;
      int p = k0 >> 4;
      const float* ap = x + ((size_t)(b * 512) + h * 16 + p) * 128 + w * 16 + lk;
      float4 av = *(const float4*)ap;
      As[lk + 0][lr] = av.x; As[lk + 1][lr] = av.y;
      As[lk + 2][lr] = av.z; As[lk + 3][lr] = av.w;
    }
    {
      const float* bp = Bw + (size_t)(bn + lr) * 256 + k0 + lk;
      float4 bv = *(const float4*)bp;
      Bs[lk + 0][lr] = bv.x; Bs[lk + 1][lr] = bv.y;
      Bs[lk + 2][lr] = bv.z; Bs[lk + 3][lr] = bv.w;
    }
    __syncthreads();
    #pragma unroll
    for (int k = 0; k < 16; ++k) {
      float4 a = *(const float4*)&As[k][tm];
      float4 b = *(const float4*)&Bs[k][tn];
      float av[4] = {a.x, a.y, a.z, a.w};
      float bv[4] = {b.x, b.y, b.z, b.w};
      #pragma unroll
      for (int i = 0; i < 4; ++i)
        #pragma unroll
        for (int j = 0; j < 4; ++j)
          acc[i][j] = fmaf(av[i], bv[j], acc[i][j]);
    }
    __syncthreads();
  }
  #pragma unroll
  for (int i = 0; i < 4; ++i) {
    int row = bm + tm + i;
    #pragma unroll
    for (int j = 0; j < 4; ++j) {
      int col = bn + tn + j;
      C[(size_t)row * kDM + col] =
          acc[i][j] + bias[col] + pos[(size_t)(row & 255) * kDM + col];
    }
  }
}

// ------------- final layernorm + fused mean-pool (atomicAdd) ---------------
__global__ __launch_bounds__(384) void lnpool_k(
    const float* __restrict__ in, float* __restrict__ pooled,
    const float* __restrict__ g, const float* __restrict__ bb) {
  int t = blockIdx.x, d = threadIdx.x;
  float v = in[(size_t)t * kDM + d];
  float s = v, s2 = v * v;
  #pragma unroll
  for (int m = 32; m >= 1; m >>= 1) {
    s  += __shfl_xor(s, m);
    s2 += __shfl_xor(s2, m);
  }
  __shared__ float ps[6], ps2[6];
  if ((d & 63) == 0) { ps[d >> 6] = s; ps2[d >> 6] = s2; }
  __syncthreads();
  float S = 0.f, S2 = 0.f;
  #pragma unroll
  for (int i = 0; i < 6; ++i) { S += ps[i]; S2 += ps2[i]; }
  float mean = S * (1.f / 384.f);
  float var  = S2 * (1.f / 384.f) - mean * mean;
  float r = rsqrtf(var + 1e-5f);
  float o = (v - mean) * r * g[d] + bb[d];
  atomicAdd(&pooled[(size_t)(t >> 8) * kDM + d], o * (1.f / 256.f));
}

// ------------- convert ALL layers' GEMM weights fp32 -> bf16 (+pool zero) --
__global__ __launch_bounds__(256) void convert_all_k(
    const float* __restrict__ w_in, const float* __restrict__ w_out,
    const float* __restrict__ w_x, unsigned short* __restrict__ dst,
    float* __restrict__ pooled_zero) {
  int layer = blockIdx.y;
  int tid = threadIdx.x;
  if (layer == 0 && blockIdx.x == 0) {
    for (int i = tid; i < kB * kDM; i += 256) pooled_zero[i] = 0.f;
  }
  int i4 = (blockIdx.x * 256 + tid) * 4;
  if (i4 >= kWTOT) return;
  const float* src;
  int off;
  if (i4 < kWIN) { src = w_in + (size_t)layer * kWIN; off = i4; }
  else if (i4 < kWIN + kWOUT) { src = w_out + (size_t)layer * kWOUT; off = i4 - kWIN; }
  else { src = w_x + (size_t)layer * kWX; off = i4 - kWIN - kWOUT; }
  float4 v = *(const float4*)(src + off);
  unsigned short o[4] = {f2bf(v.x), f2bf(v.y), f2bf(v.z), f2bf(v.w)};
  *(uint2*)(dst + (size_t)layer * kWTOT + i4) = *(const uint2*)o;
}

// ------------- in_proj with fused LayerNorm (+ proj zeroing), 64x128 -------
// xz_bf[2048,1536] = LN(tok)[2048,384] · W[1536,384]^T  (bf16 MFMA, bf16 out)
// grid (12, 32) = 384 blocks.
__global__ __launch_bounds__(256) void inproj_ln_k(
    const float* __restrict__ tok, const unsigned short* __restrict__ Bw,
    const float* __restrict__ g, const float* __restrict__ bb,
    unsigned short* __restrict__ Cbf, float* __restrict__ proj_zero) {
  __shared__ __align__(16) unsigned short As[4][64][8];
  __shared__ __align__(16) unsigned short Bs[4][128][8];
  __shared__ float smean[64], srstd[64];
  __shared__ float sg_[kDM], sb_[kDM];
  int tid = threadIdx.x;
  int bm = blockIdx.y * 64;
  int bn = blockIdx.x * 128;
  // proj zeroing for the upcoming split-K atomics (384 blocks cover it)
  {
    int bid = blockIdx.y * 12 + blockIdx.x;
    for (int i = bid * 256 + tid; i < kTok * kPROJ; i += 384 * 256)
      proj_zero[i] = 0.f;
  }
  for (int i = tid; i < kDM; i += 256) { sg_[i] = g[i]; sb_[i] = bb[i]; }
  // LN stats prepass: 4 threads per row
  {
    int r = tid >> 2, quarter = tid & 3;
    const float* rp = tok + (size_t)(bm + r) * kDM + quarter * 96;
    float s = 0.f, s2 = 0.f;
    #pragma unroll
    for (int q = 0; q < 24; ++q) {
      float4 v = ((const float4*)rp)[q];
      s  += v.x + v.y + v.z + v.w;
      s2 += v.x * v.x + v.y * v.y + v.z * v.z + v.w * v.w;
    }
    s  += __shfl_xor(s, 1);  s2 += __shfl_xor(s2, 1);
    s  += __shfl_xor(s, 2);  s2 += __shfl_xor(s2, 2);
    if (quarter == 0) {
      float mean = s * (1.f / 384.f);
      float var  = s2 * (1.f / 384.f) - mean * mean;
      smean[r] = mean;
      srstd[r] = rsqrtf(var + 1e-5f);
    }
  }
  __syncthreads();
  int wave = tid >> 6, lane = tid & 63;
  int lm = lane & 15, lq = lane >> 4;
  int wm = (wave & 1) * 32, wn = (wave >> 1) * 64;
  f32x4 acc[2][4] = {};
  for (int k0 = 0; k0 < kDM; k0 += 32) {
    int ar = tid & 63, aq = tid >> 6;  // aq 0..3 (k-quad)
    unsigned short av[8];
    {
      float mean = smean[ar], rstd = srstd[ar];
      const float* ap = tok + (size_t)(bm + ar) * kDM + k0 + aq * 8;
      float4 v0 = ((const float4*)ap)[0];
      float4 v1 = ((const float4*)ap)[1];
      float vv[8] = {v0.x, v0.y, v0.z, v0.w, v1.x, v1.y, v1.z, v1.w};
      #pragma unroll
      for (int j = 0; j < 8; ++j) {
        int k = k0 + aq * 8 + j;
        av[j] = f2bf((vv[j] - mean) * rstd * sg_[k] + sb_[k]);
      }
    }
    int br = tid & 127, bq0 = tid >> 7, bq1 = bq0 + 2;
    uint4 b0 = *(const uint4*)(Bw + (size_t)(bn + br) * kDM + k0 + bq0 * 8);
    uint4 b1 = *(const uint4*)(Bw + (size_t)(bn + br) * kDM + k0 + bq1 * 8);
    __syncthreads();
    *(uint4*)&As[aq][ar][0]  = *(const uint4*)av;
    *(uint4*)&Bs[bq0][br][0] = b0;
    *(uint4*)&Bs[bq1][br][0] = b1;
    __syncthreads();
    short8 bfrag[4];
    #pragma unroll
    for (int ni = 0; ni < 4; ++ni)
      bfrag[ni] = *(const short8*)&Bs[lq][wn + ni * 16 + lm][0];
    #pragma unroll
    for (int mi = 0; mi < 2; ++mi) {
      short8 afrag = *(const short8*)&As[lq][wm + mi * 16 + lm][0];
      #pragma unroll
      for (int ni = 0; ni < 4; ++ni)
        acc[mi][ni] = __builtin_amdgcn_mfma_f32_16x16x32_bf16(
            afrag, bfrag[ni], acc[mi][ni], 0, 0, 0);
    }
  }
  #pragma unroll
  for (int mi = 0; mi < 2; ++mi) {
    #pragma unroll
    for (int ni = 0; ni < 4; ++ni) {
      int grow0 = bm + wm + mi * 16 + lq * 4;
      int gcol = bn + wn + ni * 16 + lm;
      #pragma unroll
      for (int r = 0; r < 4; ++r)
        Cbf[(size_t)(grow0 + r) * (2 * kDI) + gcol] = f2bf(acc[mi][ni][r]);
    }
  }
}

// ------------- x_proj with fused depthwise conv + SiLU + z-gate ------------
// grid (32, 6) = 192 blocks. proj output TRANSPOSED: projT[56][2048] so the
// scan kernel can read/stage it coalesced. Side outputs unchanged.
__global__ __launch_bounds__(256) void xproj_conv_k(
    const unsigned short* __restrict__ xz, const unsigned short* __restrict__ Bw,
    const float* __restrict__ cw, const float* __restrict__ cb,
    float* __restrict__ projT, unsigned short* __restrict__ uT_bf,
    unsigned short* __restrict__ sgT_bf) {
  __shared__ __align__(16) unsigned short As[4][64][8];
  __shared__ __align__(16) unsigned short Bs[4][64][8];
  __shared__ float scw[128][4];
  __shared__ float scb[128];
  int tid = threadIdx.x;
  int bm = blockIdx.x * 64;       // token tile
  int kbase = blockIdx.y * 128;   // d chunk (split-K = 6)
  int wave = tid >> 6, lane = tid & 63;
  int lm = lane & 15, lq = lane >> 4;
  int wm = wave * 16;
  f32x4 acc[4] = {};

  if (tid < 128) {
    *(float4*)&scw[tid][0] = *(const float4*)(cw + (size_t)(kbase + tid) * 4);
    scb[tid] = cb[kbase + tid];
  }
  __syncthreads();

  int ar = tid & 63;
  int aq = tid >> 6;   // 0..3
  int t = bm + ar;
  int b = t >> 8, l = t & 255;

  for (int kt = 0; kt < 4; ++kt) {
    int k0 = kbase + kt * 32;
    int dloc = kt * 32 + aq * 8;
    int dg = kbase + dloc;
    unsigned short av[8];
    {
      float vals[4][8];
      #pragma unroll
      for (int q = 0; q < 4; ++q) {
        if (l - 3 + q >= 0) {
          uint4 r = *(const uint4*)(xz + (size_t)(t - 3 + q) * (2 * kDI) + dg);
          const unsigned short* rs = (const unsigned short*)&r;
          #pragma unroll
          for (int j = 0; j < 8; ++j) vals[q][j] = bf2f(rs[j]);
        } else {
          #pragma unroll
          for (int j = 0; j < 8; ++j) vals[q][j] = 0.f;
        }
      }
      // z-gate for the same 8 channels (row t, offset +768)
      uint4 zr = *(const uint4*)(xz + (size_t)t * (2 * kDI) + kDI + dg);
      const unsigned short* zs = (const unsigned short*)&zr;
      #pragma unroll
      for (int j = 0; j < 8; ++j) {
        float a = scb[dloc + j];
        a = fmaf(vals[0][j], scw[dloc + j][0], a);
        a = fmaf(vals[1][j], scw[dloc + j][1], a);
        a = fmaf(vals[2][j], scw[dloc + j][2], a);
        a = fmaf(vals[3][j], scw[dloc + j][3], a);
        unsigned short ub = f2bf(silu_f(a));
        av[j] = ub;
        size_t rbase = ((size_t)b * kDI + dg + j) * kL + l;
        uT_bf[rbase] = ub;
        sgT_bf[rbase] = f2bf(silu_f(bf2f(zs[j])));
      }
    }
    int br = tid & 63, bq = tid >> 6;
    uint4 b0;
    if (br < kPROJ)
      b0 = *(const uint4*)(Bw + (size_t)br * kDI + k0 + bq * 8);
    else
      b0 = make_uint4(0u, 0u, 0u, 0u);
    __syncthreads();
    *(uint4*)&As[aq][ar][0] = *(const uint4*)av;
    *(uint4*)&Bs[bq][br][0] = b0;
    __syncthreads();
    short8 afrag = *(const short8*)&As[lq][wm + lm][0];
    #pragma unroll
    for (int ni = 0; ni < 4; ++ni) {
      short8 bfrag = *(const short8*)&Bs[lq][ni * 16 + lm][0];
      acc[ni] = __builtin_amdgcn_mfma_f32_16x16x32_bf16(
          afrag, bfrag, acc[ni], 0, 0, 0);
    }
  }

  // transposed C-write: projT[gcol][token] — 4 consecutive floats per frag
  #pragma unroll
  for (int ni = 0; ni < 4; ++ni) {
    int grow0 = bm + wm + lq * 4;
    int gcol = ni * 16 + lm;
    if (gcol < kPROJ) {
      #pragma unroll
      for (int r = 0; r < 4; ++r)
        atomicAdd(&projT[(size_t)gcol * kTok + grow0 + r], acc[ni][r]);
    }
  }
}

// ------------- bf16 MFMA NT GEMM (out_proj): atomicAdd into residual -------
__global__ __launch_bounds__(256) void bgemm_out_k(
    const unsigned short* __restrict__ A, int lda,
    const unsigned short* __restrict__ B, int ldb,
    float* __restrict__ C, int ldc, int Kc) {
  __shared__ __align__(16) unsigned short As[4][128][8];
  __shared__ __align__(16) unsigned short Bs[4][128][8];
  int tid = threadIdx.x;
  int bm = blockIdx.y * 128;
  int bn = blockIdx.x * 128;
  int k_begin = blockIdx.z * Kc;
  int wave = tid >> 6, lane = tid & 63;
  int lm = lane & 15, lq = lane >> 4;
  int wm = (wave >> 1) * 64, wn = (wave & 1) * 64;
  f32x4 acc[4][4] = {};

  for (int kt = 0; kt < Kc; kt += 32) {
    int k0 = k_begin + kt;
    int ar0 = tid & 127, aq0 = tid >> 7;
    int aq1 = aq0 + 2;
    uint4 a0 = *(const uint4*)(A + (size_t)(bm + ar0) * lda + k0 + aq0 * 8);
    uint4 a1 = *(const uint4*)(A + (size_t)(bm + ar0) * lda + k0 + aq1 * 8);
    uint4 b0 = *(const uint4*)(B + (size_t)(bn + ar0) * ldb + k0 + aq0 * 8);
    uint4 b1 = *(const uint4*)(B + (size_t)(bn + ar0) * ldb + k0 + aq1 * 8);
    __syncthreads();
    *(uint4*)&As[aq0][ar0][0] = a0;
    *(uint4*)&As[aq1][ar0][0] = a1;
    *(uint4*)&Bs[aq0][ar0][0] = b0;
    *(uint4*)&Bs[aq1][ar0][0] = b1;
    __syncthreads();
    short8 bfrag[4];
    #pragma unroll
    for (int ni = 0; ni < 4; ++ni)
      bfrag[ni] = *(const short8*)&Bs[lq][wn + ni * 16 + lm][0];
    #pragma unroll
    for (int mi = 0; mi < 4; ++mi) {
      short8 afrag = *(const short8*)&As[lq][wm + mi * 16 + lm][0];
      #pragma unroll
      for (int ni = 0; ni < 4; ++ni)
        acc[mi][ni] = __builtin_amdgcn_mfma_f32_16x16x32_bf16(
            afrag, bfrag[ni], acc[mi][ni], 0, 0, 0);
    }
  }

  #pragma unroll
  for (int mi = 0; mi < 4; ++mi) {
    #pragma unroll
    for (int ni = 0; ni < 4; ++ni) {
      int grow0 = bm + wm + mi * 16 + lq * 4;
      int gcol = bn + wn + ni * 16 + lm;
      #pragma unroll
      for (int r = 0; r < 4; ++r)
        atomicAdd(&C[(size_t)(grow0 + r) * ldc + gcol], acc[mi][ni][r]);
    }
  }
}

// ------------- split-state scan v4: coalesced LDS stage from projT ---------
// projT[56][2048] lets the stage loop read 1024B-contiguous per row:
// sp[r][tid] = projT[r][b*256+tid]. dt/B/C reads then hit LDS at 2-way bank
// aliasing (stride 257; free). Same math as the verified v1/v3 scan.
__global__ __launch_bounds__(256, 3) void scansplit_k(
    const float* __restrict__ projT, const unsigned short* __restrict__ uT_bf,
    const unsigned short* __restrict__ sgT_bf, const float* __restrict__ dtw,
    const float* __restrict__ dtb, const float* __restrict__ A_log,
    const float* __restrict__ Dsk, unsigned short* __restrict__ y_bf) {
  int d0 = blockIdx.x * 4;
  int b = blockIdx.y;
  int tid = threadIdx.x;
  int dsub = tid & 3;
  int nq = (tid >> 2) & 3;   // state quarter: states nq*4 .. nq*4+3
  int c = tid >> 4;          // chunk of 16 tokens
  int d = d0 + dsub;
  __shared__ float sp[32][257];      // stage arena (dt rows 0..23, then BC)
  __shared__ float sdt[16][16][5];   // [chunk][token-in-chunk][dsub]
  __shared__ float sh[16][16][5];    // [chunk][state][dsub]
  __shared__ float sca[16][16][5];

  const float* pT = projT + (size_t)b * kL;   // +r*kTok + local_t

  // stage A: dt rows 0..23 (fully coalesced: 1KB per row per wavefront set)
  #pragma unroll
  for (int r = 0; r < 24; ++r)
    sp[r][tid] = pT[(size_t)r * kTok + tid];

  // A (pre-scaled by log2(e) so the scan uses exp2 directly)
  float Av2[4];
  {
    const float kLog2e = 1.44269504088896340736f;
    float4 v = *(const float4*)(A_log + (size_t)d * kDS + nq * 4);
    Av2[0] = -__expf(v.x) * kLog2e;
    Av2[1] = -__expf(v.y) * kLog2e;
    Av2[2] = -__expf(v.z) * kLog2e;
    Av2[3] = -__expf(v.w) * kLog2e;
  }
  float bdt = dtb[d];
  float Dv = Dsk[d];

  float wdt[24];
  {
    const float* wp = dtw + (size_t)d * kDTR;
    #pragma unroll
    for (int q = 0; q < 6; ++q) {
      float4 v = ((const float4*)wp)[q];
      wdt[q * 4 + 0] = v.x; wdt[q * 4 + 1] = v.y;
      wdt[q * 4 + 2] = v.z; wdt[q * 4 + 3] = v.w;
    }
  }

  // u: 16 bf16 tokens packed in 2 uint4, unpacked per use
  union { uint4 v[2]; unsigned short s[16]; } uu;
  {
    const unsigned short* up = uT_bf + ((size_t)b * kDI + d) * kL + c * 16;
    uu.v[0] = ((const uint4*)up)[0];
    uu.v[1] = ((const uint4*)up)[1];
  }

  __syncthreads();   // stage A visible

  // dt_proj for my 4 tokens (tk = c*16 + nq*4 + i) from LDS -> sdt
  #pragma unroll
  for (int i = 0; i < 4; ++i) {
    int tk = c * 16 + nq * 4 + i;
    float acc = bdt;
    #pragma unroll
    for (int r = 0; r < 24; ++r) acc = fmaf(sp[r][tk], wdt[r], acc);
    sdt[c][nq * 4 + i][dsub] = softplus_f(acc);
  }
  __syncthreads();   // dt reads of sp done; sdt written

  // stage B: rows 24..55 (B at sp[0..15], C at sp[16..31]) — coalesced
  #pragma unroll
  for (int r = 0; r < 32; ++r)
    sp[r][tid] = pT[(size_t)(24 + r) * kTok + tid];
  __syncthreads();   // stage B visible

  // pass 1: local chunk scan over my 4 states (all operands LDS/regs)
  float h[4] = {};
  float S = 0.f;
  #pragma unroll
  for (int i = 0; i < 16; ++i) {
    int tk = c * 16 + i;
    float dl = sdt[c][i][dsub];
    float du = dl * bf2f(uu.s[i]);
    S += dl;
    #pragma unroll
    for (int n = 0; n < 4; ++n) {
      float a = exp2f(dl * Av2[n]);
      h[n] = fmaf(a, h[n], du * sp[nq * 4 + n][tk]);
    }
  }
  {
    int nrow = nq * 4;
    #pragma unroll
    for (int n = 0; n < 4; ++n) {
      sh[c][nrow + n][dsub] = h[n];
      sca[c][nrow + n][dsub] = exp2f(S * Av2[n]);  // == prod of a's
    }
  }
  __syncthreads();

  // chunk-prefix combine (same address across the wave -> LDS broadcast)
  float h0[4] = {};
  {
    int nrow = nq * 4;
    for (int j = 0; j < c; ++j) {
      #pragma unroll
      for (int n = 0; n < 4; ++n)
        h0[n] = fmaf(sca[j][nrow + n][dsub], h0[n], sh[j][nrow + n][dsub]);
    }
  }

  // z-gate for nq==0 quarter: packed bf16
  union { uint4 v[2]; unsigned short s[16]; } zz;
  zz.v[0] = make_uint4(0u, 0u, 0u, 0u);
  zz.v[1] = make_uint4(0u, 0u, 0u, 0u);
  if (nq == 0) {
    const unsigned short* sp2 = sgT_bf + ((size_t)b * kDI + d) * kL + c * 16;
    zz.v[0] = ((const uint4*)sp2)[0];
    zz.v[1] = ((const uint4*)sp2)[1];
  }

  // pass 2: true scan from h0; partial y over my 4 states; 2 shuffles; store
  unsigned short* yp = y_bf + (size_t)(b * kL + c * 16) * kDI + d;
  #pragma unroll
  for (int i = 0; i < 16; ++i) {
    int tk = c * 16 + i;
    float dl = sdt[c][i][dsub];
    float uv = bf2f(uu.s[i]);
    float du = dl * uv;
    float yv = 0.f;
    #pragma unroll
    for (int n = 0; n < 4; ++n) {
      float a = exp2f(dl * Av2[n]);
      h0[n] = fmaf(a, h0[n], du * sp[nq * 4 + n][tk]);
      yv = fmaf(h0[n], sp[16 + nq * 4 + n][tk], yv);
    }
    yv += __shfl_xor(yv, 4);
    yv += __shfl_xor(yv, 8);
    if (nq == 0) yp[(size_t)i * kDI] = f2bf((yv + uv * Dv) * bf2f(zz.s[i]));
  }
}

// ---------------- head ----------------
__global__ __launch_bounds__(64) void head_k(
    const float* __restrict__ pooled, const float* __restrict__ hw,
    const float* __restrict__ hb, float* __restrict__ out) {
  int b = blockIdx.x >> 2, c = blockIdx.x & 3;
  int lane = threadIdx.x;
  float acc = 0.f;
  for (int dd = lane; dd < kDM; dd += 64)
    acc = fmaf(pooled[b * kDM + dd], hw[c * kDM + dd], acc);
  #pragma unroll
  for (int m = 32; m >= 1; m >>= 1) acc += __shfl_xor(acc, m);
  if (lane == 0) out[b * 4 + c] = acc + hb[c];
}

}  // namespace

extern "C" void kernel_launch(void* const* d_in, const int* in_sizes, int n_in,
                              void* d_out, int out_size, void* d_ws, size_t ws_size,
                              hipStream_t stream) {
  (void)in_sizes; (void)n_in; (void)out_size; (void)ws_size;
  const float* x        = (const float*)d_in[0];
  const float* patch_w  = (const float*)d_in[1];
  const float* patch_b  = (const float*)d_in[2];
  const float* pos      = (const float*)d_in[3];
  const float* ln_g     = (const float*)d_in[4];
  const float* ln_b     = (const float*)d_in[5];
  const float* in_w     = (const float*)d_in[6];
  const float* conv_w   = (const float*)d_in[7];
  const float* conv_b   = (const float*)d_in[8];
  const float* xproj_w  = (const float*)d_in[9];
  const float* dtproj_w = (const float*)d_in[10];
  const float* dtproj_b = (const float*)d_in[11];
  const float* A_log    = (const float*)d_in[12];
  const float* Dskip    = (const float*)d_in[13];
  const float* out_w    = (const float*)d_in[14];
  const float* fn_g     = (const float*)d_in[15];
  const float* fn_b     = (const float*)d_in[16];
  const float* head_w   = (const float*)d_in[17];
  const float* head_b   = (const float*)d_in[18];
  float* out = (float*)d_out;

  float* ws = (float*)d_ws;
  float* tok    = ws; ws += kTok * kDM;       // fp32 residual
  float* projT  = ws; ws += kTok * kPROJ;     // TRANSPOSED [56][2048]
  float* pooled = ws; ws += kB * kDM;
  unsigned short* xz_bf  = (unsigned short*)ws; ws += kTok * 2 * kDI / 2;
  unsigned short* uT_bf  = (unsigned short*)ws; ws += kTok * kDI / 2;
  unsigned short* sgT_bf = (unsigned short*)ws; ws += kTok * kDI / 2;
  unsigned short* y_bf   = (unsigned short*)ws; ws += kTok * kDI / 2;
  unsigned short* w_bf   = (unsigned short*)ws; ws += (size_t)kNL * kWTOT / 2;

  // all-layer weight cast + pooled zero-init (once per call)
  convert_all_k<<<dim3(kWTOT / 4 / 256, kNL), 256, 0, stream>>>(
      in_w, out_w, xproj_w, w_bf, pooled);

  // Patch embedding fused: im2col + GEMM + bias + pos
  patch_gemm_k<<<dim3(6, 32), 256, 0, stream>>>(x, patch_w, patch_b, pos, tok);

  for (int layer = 0; layer < kNL; ++layer) {
    const unsigned short* wl = w_bf + (size_t)layer * kWTOT;
    // in_proj with fused LN (+ projT zero): LN(tok) x W^T -> xz_bf (384 blk)
    inproj_ln_k<<<dim3(12, 32), 256, 0, stream>>>(
        tok, wl, ln_g + layer * kDM, ln_b + layer * kDM, xz_bf, projT);
    // x_proj with fused conv+SiLU+z-gate: projT += (u·Wx^T)^T ; uT_bf, sgT_bf
    xproj_conv_k<<<dim3(32, 6), 256, 0, stream>>>(
        xz_bf, wl + kWIN + kWOUT, conv_w + layer * kDI * 4,
        conv_b + layer * kDI, projT, uT_bf, sgT_bf);
    // split-state scan v4 (coalesced LDS stage) + fused dt_proj -> y_bf
    scansplit_k<<<dim3(kDI / 4, kB), 256, 0, stream>>>(
        projT, uT_bf, sgT_bf, dtproj_w + (size_t)layer * kDI * kDTR,
        dtproj_b + layer * kDI, A_log + (size_t)layer * kDI * kDS,
        Dskip + layer * kDI, y_bf);
    // out_proj (MFMA, split-K=4, atomic into residual): tok += y x W^T
    bgemm_out_k<<<dim3(3, 16, 4), 256, 0, stream>>>(
        y_bf, kDI, wl + kWIN, kDI, tok, kDM, kDI / 4);
  }

  // final LN + fused mean-pool (atomicAdd into pre-zeroed pooled)
  lnpool_k<<<kTok, kDM, 0, stream>>>(tok, pooled, fn_g, fn_b);
  head_k<<<kB * 4, 64, 0, stream>>>(pooled, head_w, head_b, out);
}

// Round 7
// 1176.309 us; speedup vs baseline: 3.0712x; 1.0613x over previous
//
#include <hip/hip_runtime.h>
#include <math.h>

namespace {

constexpr int kB   = 8;
constexpr int kL   = 256;
constexpr int kTok = 2048;   // B*L
constexpr int kDM  = 384;
constexpr int kDI  = 768;
constexpr int kDS  = 16;
constexpr int kDTR = 24;
constexpr int kPROJ = 56;    // DTR + 2*DS
constexpr int kNL  = 12;

constexpr int kWIN  = 2 * kDI * kDM;   // 589824 in_proj weights/layer
constexpr int kWOUT = kDM * kDI;       // 294912
constexpr int kWX   = kPROJ * kDI;     // 43008
constexpr int kWTOT = kWIN + kWOUT + kWX;  // 927744

typedef float f32x4 __attribute__((ext_vector_type(4)));
typedef short short8 __attribute__((ext_vector_type(8)));

__device__ __forceinline__ float softplus_f(float x) {
  return (x > 20.f) ? x : log1pf(__expf(x));
}
__device__ __forceinline__ float silu_f(float x) {
  return x / (1.f + __expf(-x));
}
__device__ __forceinline__ unsigned short f2bf(float f) {
  union { float f; unsigned u; } v; v.f = f;
  unsigned r = v.u + 0x7FFFu + ((v.u >> 16) & 1u);
  return (unsigned short)(r >> 16);
}
__device__ __forceinline__ float bf2f(unsigned short u) {
  return __uint_as_float((unsigned)u << 16);
}

// ------------- patch embed GEMM: tok = im2col(x)·patch_w^T + b + pos -------
__global__ __launch_bounds__(256) void patch_gemm_k(
    const float* __restrict__ x, const float* __restrict__ Bw,
    const float* __restrict__ bias, const float* __restrict__ pos,
    float* __restrict__ C) {
  __shared__ float As[16][68];
  __shared__ float Bs[16][68];
  int tid = threadIdx.x;
  int bm = blockIdx.y * 64;
  int bn = blockIdx.x * 64;
  int lr = tid >> 2;
  int lk = (tid & 3) << 2;
  int tm = (tid >> 4) << 2;
  int tn = (tid & 15) << 2;
  float acc[4][4] = {};
  for (int k0 = 0; k0 < 256; k0 += 16) {
    {
      int token = bm + lr;
      int b = token >> 8, l = token & 255;
      int h = l >> 3, w = l & 7;
      int p = k0 >> 4;
      const float* ap = x + ((size_t)(b * 512) + h * 16 + p) * 128 + w * 16 + lk;
      float4 av = *(const float4*)ap;
      As[lk + 0][lr] = av.x; As[lk + 1][lr] = av.y;
      As[lk + 2][lr] = av.z; As[lk + 3][lr] = av.w;
    }
    {
      const float* bp = Bw + (size_t)(bn + lr) * 256 + k0 + lk;
      float4 bv = *(const float4*)bp;
      Bs[lk + 0][lr] = bv.x; Bs[lk + 1][lr] = bv.y;
      Bs[lk + 2][lr] = bv.z; Bs[lk + 3][lr] = bv.w;
    }
    __syncthreads();
    #pragma unroll
    for (int k = 0; k < 16; ++k) {
      float4 a = *(const float4*)&As[k][tm];
      float4 b = *(const float4*)&Bs[k][tn];
      float av[4] = {a.x, a.y, a.z, a.w};
      float bv[4] = {b.x, b.y, b.z, b.w};
      #pragma unroll
      for (int i = 0; i < 4; ++i)
        #pragma unroll
        for (int j = 0; j < 4; ++j)
          acc[i][j] = fmaf(av[i], bv[j], acc[i][j]);
    }
    __syncthreads();
  }
  #pragma unroll
  for (int i = 0; i < 4; ++i) {
    int row = bm + tm + i;
    #pragma unroll
    for (int j = 0; j < 4; ++j) {
      int col = bn + tn + j;
      C[(size_t)row * kDM + col] =
          acc[i][j] + bias[col] + pos[(size_t)(row & 255) * kDM + col];
    }
  }
}

// ------------- final layernorm + fused mean-pool (atomicAdd) ---------------
__global__ __launch_bounds__(384) void lnpool_k(
    const float* __restrict__ in, float* __restrict__ pooled,
    const float* __restrict__ g, const float* __restrict__ bb) {
  int t = blockIdx.x, d = threadIdx.x;
  float v = in[(size_t)t * kDM + d];
  float s = v, s2 = v * v;
  #pragma unroll
  for (int m = 32; m >= 1; m >>= 1) {
    s  += __shfl_xor(s, m);
    s2 += __shfl_xor(s2, m);
  }
  __shared__ float ps[6], ps2[6];
  if ((d & 63) == 0) { ps[d >> 6] = s; ps2[d >> 6] = s2; }
  __syncthreads();
  float S = 0.f, S2 = 0.f;
  #pragma unroll
  for (int i = 0; i < 6; ++i) { S += ps[i]; S2 += ps2[i]; }
  float mean = S * (1.f / 384.f);
  float var  = S2 * (1.f / 384.f) - mean * mean;
  float r = rsqrtf(var + 1e-5f);
  float o = (v - mean) * r * g[d] + bb[d];
  atomicAdd(&pooled[(size_t)(t >> 8) * kDM + d], o * (1.f / 256.f));
}

// ------------- convert ALL layers' GEMM weights fp32 -> bf16 (+pool zero) --
__global__ __launch_bounds__(256) void convert_all_k(
    const float* __restrict__ w_in, const float* __restrict__ w_out,
    const float* __restrict__ w_x, unsigned short* __restrict__ dst,
    float* __restrict__ pooled_zero) {
  int layer = blockIdx.y;
  int tid = threadIdx.x;
  if (layer == 0 && blockIdx.x == 0) {
    for (int i = tid; i < kB * kDM; i += 256) pooled_zero[i] = 0.f;
  }
  int i4 = (blockIdx.x * 256 + tid) * 4;
  if (i4 >= kWTOT) return;
  const float* src;
  int off;
  if (i4 < kWIN) { src = w_in + (size_t)layer * kWIN; off = i4; }
  else if (i4 < kWIN + kWOUT) { src = w_out + (size_t)layer * kWOUT; off = i4 - kWIN; }
  else { src = w_x + (size_t)layer * kWX; off = i4 - kWIN - kWOUT; }
  float4 v = *(const float4*)(src + off);
  unsigned short o[4] = {f2bf(v.x), f2bf(v.y), f2bf(v.z), f2bf(v.w)};
  *(uint2*)(dst + (size_t)layer * kWTOT + i4) = *(const uint2*)o;
}

// ------------- in_proj with fused LayerNorm (+ proj zeroing), 64x128 -------
// xz_bf[2048,1536] = LN(tok)[2048,384] · W[1536,384]^T  (bf16 MFMA, bf16 out)
// grid (12, 32) = 384 blocks.
__global__ __launch_bounds__(256) void inproj_ln_k(
    const float* __restrict__ tok, const unsigned short* __restrict__ Bw,
    const float* __restrict__ g, const float* __restrict__ bb,
    unsigned short* __restrict__ Cbf, float* __restrict__ proj_zero) {
  __shared__ __align__(16) unsigned short As[4][64][8];
  __shared__ __align__(16) unsigned short Bs[4][128][8];
  __shared__ float smean[64], srstd[64];
  __shared__ float sg_[kDM], sb_[kDM];
  int tid = threadIdx.x;
  int bm = blockIdx.y * 64;
  int bn = blockIdx.x * 128;
  // proj zeroing for the upcoming split-K atomics (384 blocks cover it)
  {
    int bid = blockIdx.y * 12 + blockIdx.x;
    for (int i = bid * 256 + tid; i < kTok * kPROJ; i += 384 * 256)
      proj_zero[i] = 0.f;
  }
  for (int i = tid; i < kDM; i += 256) { sg_[i] = g[i]; sb_[i] = bb[i]; }
  // LN stats prepass: 4 threads per row
  {
    int r = tid >> 2, quarter = tid & 3;
    const float* rp = tok + (size_t)(bm + r) * kDM + quarter * 96;
    float s = 0.f, s2 = 0.f;
    #pragma unroll
    for (int q = 0; q < 24; ++q) {
      float4 v = ((const float4*)rp)[q];
      s  += v.x + v.y + v.z + v.w;
      s2 += v.x * v.x + v.y * v.y + v.z * v.z + v.w * v.w;
    }
    s  += __shfl_xor(s, 1);  s2 += __shfl_xor(s2, 1);
    s  += __shfl_xor(s, 2);  s2 += __shfl_xor(s2, 2);
    if (quarter == 0) {
      float mean = s * (1.f / 384.f);
      float var  = s2 * (1.f / 384.f) - mean * mean;
      smean[r] = mean;
      srstd[r] = rsqrtf(var + 1e-5f);
    }
  }
  __syncthreads();
  int wave = tid >> 6, lane = tid & 63;
  int lm = lane & 15, lq = lane >> 4;
  int wm = (wave & 1) * 32, wn = (wave >> 1) * 64;
  f32x4 acc[2][4] = {};
  for (int k0 = 0; k0 < kDM; k0 += 32) {
    int ar = tid & 63, aq = tid >> 6;  // aq 0..3 (k-quad)
    unsigned short av[8];
    {
      float mean = smean[ar], rstd = srstd[ar];
      const float* ap = tok + (size_t)(bm + ar) * kDM + k0 + aq * 8;
      float4 v0 = ((const float4*)ap)[0];
      float4 v1 = ((const float4*)ap)[1];
      float vv[8] = {v0.x, v0.y, v0.z, v0.w, v1.x, v1.y, v1.z, v1.w};
      #pragma unroll
      for (int j = 0; j < 8; ++j) {
        int k = k0 + aq * 8 + j;
        av[j] = f2bf((vv[j] - mean) * rstd * sg_[k] + sb_[k]);
      }
    }
    int br = tid & 127, bq0 = tid >> 7, bq1 = bq0 + 2;
    uint4 b0 = *(const uint4*)(Bw + (size_t)(bn + br) * kDM + k0 + bq0 * 8);
    uint4 b1 = *(const uint4*)(Bw + (size_t)(bn + br) * kDM + k0 + bq1 * 8);
    __syncthreads();
    *(uint4*)&As[aq][ar][0]  = *(const uint4*)av;
    *(uint4*)&Bs[bq0][br][0] = b0;
    *(uint4*)&Bs[bq1][br][0] = b1;
    __syncthreads();
    short8 bfrag[4];
    #pragma unroll
    for (int ni = 0; ni < 4; ++ni)
      bfrag[ni] = *(const short8*)&Bs[lq][wn + ni * 16 + lm][0];
    #pragma unroll
    for (int mi = 0; mi < 2; ++mi) {
      short8 afrag = *(const short8*)&As[lq][wm + mi * 16 + lm][0];
      #pragma unroll
      for (int ni = 0; ni < 4; ++ni)
        acc[mi][ni] = __builtin_amdgcn_mfma_f32_16x16x32_bf16(
            afrag, bfrag[ni], acc[mi][ni], 0, 0, 0);
    }
  }
  #pragma unroll
  for (int mi = 0; mi < 2; ++mi) {
    #pragma unroll
    for (int ni = 0; ni < 4; ++ni) {
      int grow0 = bm + wm + mi * 16 + lq * 4;
      int gcol = bn + wn + ni * 16 + lm;
      #pragma unroll
      for (int r = 0; r < 4; ++r)
        Cbf[(size_t)(grow0 + r) * (2 * kDI) + gcol] = f2bf(acc[mi][ni][r]);
    }
  }
}

// ------------- x_proj with fused depthwise conv + SiLU + z-gate ------------
// grid (32, 6) = 192 blocks. proj output TRANSPOSED projT[56][2048], but the
// atomics are now routed through an LDS transpose tile so each wave's
// atomicAdds hit contiguous 256B runs (r5's lane-scatter regression fixed).
__global__ __launch_bounds__(256) void xproj_conv_k(
    const unsigned short* __restrict__ xz, const unsigned short* __restrict__ Bw,
    const float* __restrict__ cw, const float* __restrict__ cb,
    float* __restrict__ projT, unsigned short* __restrict__ uT_bf,
    unsigned short* __restrict__ sgT_bf) {
  __shared__ __align__(16) unsigned short As[4][64][8];
  __shared__ __align__(16) unsigned short Bs[4][64][8];
  __shared__ float scw[128][4];
  __shared__ float scb[128];
  __shared__ float sC[kPROJ][73];   // C transpose tile (pad 73: ~2-way banks)
  int tid = threadIdx.x;
  int bm = blockIdx.x * 64;       // token tile
  int kbase = blockIdx.y * 128;   // d chunk (split-K = 6)
  int wave = tid >> 6, lane = tid & 63;
  int lm = lane & 15, lq = lane >> 4;
  int wm = wave * 16;
  f32x4 acc[4] = {};

  if (tid < 128) {
    *(float4*)&scw[tid][0] = *(const float4*)(cw + (size_t)(kbase + tid) * 4);
    scb[tid] = cb[kbase + tid];
  }
  __syncthreads();

  int ar = tid & 63;
  int aq = tid >> 6;   // 0..3
  int t = bm + ar;
  int b = t >> 8, l = t & 255;

  for (int kt = 0; kt < 4; ++kt) {
    int k0 = kbase + kt * 32;
    int dloc = kt * 32 + aq * 8;
    int dg = kbase + dloc;
    unsigned short av[8];
    {
      float vals[4][8];
      #pragma unroll
      for (int q = 0; q < 4; ++q) {
        if (l - 3 + q >= 0) {
          uint4 r = *(const uint4*)(xz + (size_t)(t - 3 + q) * (2 * kDI) + dg);
          const unsigned short* rs = (const unsigned short*)&r;
          #pragma unroll
          for (int j = 0; j < 8; ++j) vals[q][j] = bf2f(rs[j]);
        } else {
          #pragma unroll
          for (int j = 0; j < 8; ++j) vals[q][j] = 0.f;
        }
      }
      // z-gate for the same 8 channels (row t, offset +768)
      uint4 zr = *(const uint4*)(xz + (size_t)t * (2 * kDI) + kDI + dg);
      const unsigned short* zs = (const unsigned short*)&zr;
      #pragma unroll
      for (int j = 0; j < 8; ++j) {
        float a = scb[dloc + j];
        a = fmaf(vals[0][j], scw[dloc + j][0], a);
        a = fmaf(vals[1][j], scw[dloc + j][1], a);
        a = fmaf(vals[2][j], scw[dloc + j][2], a);
        a = fmaf(vals[3][j], scw[dloc + j][3], a);
        unsigned short ub = f2bf(silu_f(a));
        av[j] = ub;
        size_t rbase = ((size_t)b * kDI + dg + j) * kL + l;
        uT_bf[rbase] = ub;
        sgT_bf[rbase] = f2bf(silu_f(bf2f(zs[j])));
      }
    }
    int br = tid & 63, bq = tid >> 6;
    uint4 b0;
    if (br < kPROJ)
      b0 = *(const uint4*)(Bw + (size_t)br * kDI + k0 + bq * 8);
    else
      b0 = make_uint4(0u, 0u, 0u, 0u);
    __syncthreads();
    *(uint4*)&As[aq][ar][0] = *(const uint4*)av;
    *(uint4*)&Bs[bq][br][0] = b0;
    __syncthreads();
    short8 afrag = *(const short8*)&As[lq][wm + lm][0];
    #pragma unroll
    for (int ni = 0; ni < 4; ++ni) {
      short8 bfrag = *(const short8*)&Bs[lq][ni * 16 + lm][0];
      acc[ni] = __builtin_amdgcn_mfma_f32_16x16x32_bf16(
          afrag, bfrag, acc[ni], 0, 0, 0);
    }
  }

  // C fragments -> LDS transpose tile (each thread writes its own cells)
  #pragma unroll
  for (int ni = 0; ni < 4; ++ni) {
    int gcol = ni * 16 + lm;
    if (gcol < kPROJ) {
      int trow = wm + lq * 4;
      #pragma unroll
      for (int r = 0; r < 4; ++r)
        sC[gcol][trow + r] = acc[ni][r];
    }
  }
  __syncthreads();
  // coalesced atomics: lanes cover 64 consecutive tokens per proj row
  for (int i = tid; i < kPROJ * 64; i += 256) {
    int row = i >> 6, tt = i & 63;
    atomicAdd(&projT[(size_t)row * kTok + bm + tt], sC[row][tt]);
  }
}

// ------------- bf16 MFMA NT GEMM (out_proj): atomicAdd into residual -------
__global__ __launch_bounds__(256) void bgemm_out_k(
    const unsigned short* __restrict__ A, int lda,
    const unsigned short* __restrict__ B, int ldb,
    float* __restrict__ C, int ldc, int Kc) {
  __shared__ __align__(16) unsigned short As[4][128][8];
  __shared__ __align__(16) unsigned short Bs[4][128][8];
  int tid = threadIdx.x;
  int bm = blockIdx.y * 128;
  int bn = blockIdx.x * 128;
  int k_begin = blockIdx.z * Kc;
  int wave = tid >> 6, lane = tid & 63;
  int lm = lane & 15, lq = lane >> 4;
  int wm = (wave >> 1) * 64, wn = (wave & 1) * 64;
  f32x4 acc[4][4] = {};

  for (int kt = 0; kt < Kc; kt += 32) {
    int k0 = k_begin + kt;
    int ar0 = tid & 127, aq0 = tid >> 7;
    int aq1 = aq0 + 2;
    uint4 a0 = *(const uint4*)(A + (size_t)(bm + ar0) * lda + k0 + aq0 * 8);
    uint4 a1 = *(const uint4*)(A + (size_t)(bm + ar0) * lda + k0 + aq1 * 8);
    uint4 b0 = *(const uint4*)(B + (size_t)(bn + ar0) * ldb + k0 + aq0 * 8);
    uint4 b1 = *(const uint4*)(B + (size_t)(bn + ar0) * ldb + k0 + aq1 * 8);
    __syncthreads();
    *(uint4*)&As[aq0][ar0][0] = a0;
    *(uint4*)&As[aq1][ar0][0] = a1;
    *(uint4*)&Bs[aq0][ar0][0] = b0;
    *(uint4*)&Bs[aq1][ar0][0] = b1;
    __syncthreads();
    short8 bfrag[4];
    #pragma unroll
    for (int ni = 0; ni < 4; ++ni)
      bfrag[ni] = *(const short8*)&Bs[lq][wn + ni * 16 + lm][0];
    #pragma unroll
    for (int mi = 0; mi < 4; ++mi) {
      short8 afrag = *(const short8*)&As[lq][wm + mi * 16 + lm][0];
      #pragma unroll
      for (int ni = 0; ni < 4; ++ni)
        acc[mi][ni] = __builtin_amdgcn_mfma_f32_16x16x32_bf16(
            afrag, bfrag[ni], acc[mi][ni], 0, 0, 0);
    }
  }

  #pragma unroll
  for (int mi = 0; mi < 4; ++mi) {
    #pragma unroll
    for (int ni = 0; ni < 4; ++ni) {
      int grow0 = bm + wm + mi * 16 + lq * 4;
      int gcol = bn + wn + ni * 16 + lm;
      #pragma unroll
      for (int r = 0; r < 4; ++r)
        atomicAdd(&C[(size_t)(grow0 + r) * ldc + gcol], acc[mi][ni][r]);
    }
  }
}

// ------------- split-state scan v4: coalesced LDS stage from projT ---------
// projT[56][2048] lets the stage loop read 1024B-contiguous per row:
// sp[r][tid] = projT[r][b*256+tid]. dt/B/C reads then hit LDS at 2-way bank
// aliasing (stride 257; free). Same math as the verified v1/v3 scan.
__global__ __launch_bounds__(256, 3) void scansplit_k(
    const float* __restrict__ projT, const unsigned short* __restrict__ uT_bf,
    const unsigned short* __restrict__ sgT_bf, const float* __restrict__ dtw,
    const float* __restrict__ dtb, const float* __restrict__ A_log,
    const float* __restrict__ Dsk, unsigned short* __restrict__ y_bf) {
  int d0 = blockIdx.x * 4;
  int b = blockIdx.y;
  int tid = threadIdx.x;
  int dsub = tid & 3;
  int nq = (tid >> 2) & 3;   // state quarter: states nq*4 .. nq*4+3
  int c = tid >> 4;          // chunk of 16 tokens
  int d = d0 + dsub;
  __shared__ float sp[32][257];      // stage arena (dt rows 0..23, then BC)
  __shared__ float sdt[16][16][5];   // [chunk][token-in-chunk][dsub]
  __shared__ float sh[16][16][5];    // [chunk][state][dsub]
  __shared__ float sca[16][16][5];

  const float* pT = projT + (size_t)b * kL;   // +r*kTok + local_t

  // stage A: dt rows 0..23 (fully coalesced: 1KB per row per wavefront set)
  #pragma unroll
  for (int r = 0; r < 24; ++r)
    sp[r][tid] = pT[(size_t)r * kTok + tid];

  // A (pre-scaled by log2(e) so the scan uses exp2 directly)
  float Av2[4];
  {
    const float kLog2e = 1.44269504088896340736f;
    float4 v = *(const float4*)(A_log + (size_t)d * kDS + nq * 4);
    Av2[0] = -__expf(v.x) * kLog2e;
    Av2[1] = -__expf(v.y) * kLog2e;
    Av2[2] = -__expf(v.z) * kLog2e;
    Av2[3] = -__expf(v.w) * kLog2e;
  }
  float bdt = dtb[d];
  float Dv = Dsk[d];

  float wdt[24];
  {
    const float* wp = dtw + (size_t)d * kDTR;
    #pragma unroll
    for (int q = 0; q < 6; ++q) {
      float4 v = ((const float4*)wp)[q];
      wdt[q * 4 + 0] = v.x; wdt[q * 4 + 1] = v.y;
      wdt[q * 4 + 2] = v.z; wdt[q * 4 + 3] = v.w;
    }
  }

  // u: 16 bf16 tokens packed in 2 uint4, unpacked per use
  union { uint4 v[2]; unsigned short s[16]; } uu;
  {
    const unsigned short* up = uT_bf + ((size_t)b * kDI + d) * kL + c * 16;
    uu.v[0] = ((const uint4*)up)[0];
    uu.v[1] = ((const uint4*)up)[1];
  }

  __syncthreads();   // stage A visible

  // dt_proj for my 4 tokens (tk = c*16 + nq*4 + i) from LDS -> sdt
  #pragma unroll
  for (int i = 0; i < 4; ++i) {
    int tk = c * 16 + nq * 4 + i;
    float acc = bdt;
    #pragma unroll
    for (int r = 0; r < 24; ++r) acc = fmaf(sp[r][tk], wdt[r], acc);
    sdt[c][nq * 4 + i][dsub] = softplus_f(acc);
  }
  __syncthreads();   // dt reads of sp done; sdt written

  // stage B: rows 24..55 (B at sp[0..15], C at sp[16..31]) — coalesced
  #pragma unroll
  for (int r = 0; r < 32; ++r)
    sp[r][tid] = pT[(size_t)(24 + r) * kTok + tid];
  __syncthreads();   // stage B visible

  // pass 1: local chunk scan over my 4 states (all operands LDS/regs)
  float h[4] = {};
  float S = 0.f;
  #pragma unroll
  for (int i = 0; i < 16; ++i) {
    int tk = c * 16 + i;
    float dl = sdt[c][i][dsub];
    float du = dl * bf2f(uu.s[i]);
    S += dl;
    #pragma unroll
    for (int n = 0; n < 4; ++n) {
      float a = exp2f(dl * Av2[n]);
      h[n] = fmaf(a, h[n], du * sp[nq * 4 + n][tk]);
    }
  }
  {
    int nrow = nq * 4;
    #pragma unroll
    for (int n = 0; n < 4; ++n) {
      sh[c][nrow + n][dsub] = h[n];
      sca[c][nrow + n][dsub] = exp2f(S * Av2[n]);  // == prod of a's
    }
  }
  __syncthreads();

  // chunk-prefix combine (same address across the wave -> LDS broadcast)
  float h0[4] = {};
  {
    int nrow = nq * 4;
    for (int j = 0; j < c; ++j) {
      #pragma unroll
      for (int n = 0; n < 4; ++n)
        h0[n] = fmaf(sca[j][nrow + n][dsub], h0[n], sh[j][nrow + n][dsub]);
    }
  }

  // z-gate for nq==0 quarter: packed bf16
  union { uint4 v[2]; unsigned short s[16]; } zz;
  zz.v[0] = make_uint4(0u, 0u, 0u, 0u);
  zz.v[1] = make_uint4(0u, 0u, 0u, 0u);
  if (nq == 0) {
    const unsigned short* sp2 = sgT_bf + ((size_t)b * kDI + d) * kL + c * 16;
    zz.v[0] = ((const uint4*)sp2)[0];
    zz.v[1] = ((const uint4*)sp2)[1];
  }

  // pass 2: true scan from h0; partial y over my 4 states; 2 shuffles; store
  unsigned short* yp = y_bf + (size_t)(b * kL + c * 16) * kDI + d;
  #pragma unroll
  for (int i = 0; i < 16; ++i) {
    int tk = c * 16 + i;
    float dl = sdt[c][i][dsub];
    float uv = bf2f(uu.s[i]);
    float du = dl * uv;
    float yv = 0.f;
    #pragma unroll
    for (int n = 0; n < 4; ++n) {
      float a = exp2f(dl * Av2[n]);
      h0[n] = fmaf(a, h0[n], du * sp[nq * 4 + n][tk]);
      yv = fmaf(h0[n], sp[16 + nq * 4 + n][tk], yv);
    }
    yv += __shfl_xor(yv, 4);
    yv += __shfl_xor(yv, 8);
    if (nq == 0) yp[(size_t)i * kDI] = f2bf((yv + uv * Dv) * bf2f(zz.s[i]));
  }
}

// ---------------- head ----------------
__global__ __launch_bounds__(64) void head_k(
    const float* __restrict__ pooled, const float* __restrict__ hw,
    const float* __restrict__ hb, float* __restrict__ out) {
  int b = blockIdx.x >> 2, c = blockIdx.x & 3;
  int lane = threadIdx.x;
  float acc = 0.f;
  for (int dd = lane; dd < kDM; dd += 64)
    acc = fmaf(pooled[b * kDM + dd], hw[c * kDM + dd], acc);
  #pragma unroll
  for (int m = 32; m >= 1; m >>= 1) acc += __shfl_xor(acc, m);
  if (lane == 0) out[b * 4 + c] = acc + hb[c];
}

}  // namespace

extern "C" void kernel_launch(void* const* d_in, const int* in_sizes, int n_in,
                              void* d_out, int out_size, void* d_ws, size_t ws_size,
                              hipStream_t stream) {
  (void)in_sizes; (void)n_in; (void)out_size; (void)ws_size;
  const float* x        = (const float*)d_in[0];
  const float* patch_w  = (const float*)d_in[1];
  const float* patch_b  = (const float*)d_in[2];
  const float* pos      = (const float*)d_in[3];
  const float* ln_g     = (const float*)d_in[4];
  const float* ln_b     = (const float*)d_in[5];
  const float* in_w     = (const float*)d_in[6];
  const float* conv_w   = (const float*)d_in[7];
  const float* conv_b   = (const float*)d_in[8];
  const float* xproj_w  = (const float*)d_in[9];
  const float* dtproj_w = (const float*)d_in[10];
  const float* dtproj_b = (const float*)d_in[11];
  const float* A_log    = (const float*)d_in[12];
  const float* Dskip    = (const float*)d_in[13];
  const float* out_w    = (const float*)d_in[14];
  const float* fn_g     = (const float*)d_in[15];
  const float* fn_b     = (const float*)d_in[16];
  const float* head_w   = (const float*)d_in[17];
  const float* head_b   = (const float*)d_in[18];
  float* out = (float*)d_out;

  float* ws = (float*)d_ws;
  float* tok    = ws; ws += kTok * kDM;       // fp32 residual
  float* projT  = ws; ws += kTok * kPROJ;     // TRANSPOSED [56][2048]
  float* pooled = ws; ws += kB * kDM;
  unsigned short* xz_bf  = (unsigned short*)ws; ws += kTok * 2 * kDI / 2;
  unsigned short* uT_bf  = (unsigned short*)ws; ws += kTok * kDI / 2;
  unsigned short* sgT_bf = (unsigned short*)ws; ws += kTok * kDI / 2;
  unsigned short* y_bf   = (unsigned short*)ws; ws += kTok * kDI / 2;
  unsigned short* w_bf   = (unsigned short*)ws; ws += (size_t)kNL * kWTOT / 2;

  // all-layer weight cast + pooled zero-init (once per call)
  convert_all_k<<<dim3(kWTOT / 4 / 256, kNL), 256, 0, stream>>>(
      in_w, out_w, xproj_w, w_bf, pooled);

  // Patch embedding fused: im2col + GEMM + bias + pos
  patch_gemm_k<<<dim3(6, 32), 256, 0, stream>>>(x, patch_w, patch_b, pos, tok);

  for (int layer = 0; layer < kNL; ++layer) {
    const unsigned short* wl = w_bf + (size_t)layer * kWTOT;
    // in_proj with fused LN (+ projT zero): LN(tok) x W^T -> xz_bf (384 blk)
    inproj_ln_k<<<dim3(12, 32), 256, 0, stream>>>(
        tok, wl, ln_g + layer * kDM, ln_b + layer * kDM, xz_bf, projT);
    // x_proj with fused conv+SiLU+z-gate: projT += (u·Wx^T)^T ; uT_bf, sgT_bf
    xproj_conv_k<<<dim3(32, 6), 256, 0, stream>>>(
        xz_bf, wl + kWIN + kWOUT, conv_w + layer * kDI * 4,
        conv_b + layer * kDI, projT, uT_bf, sgT_bf);
    // split-state scan v4 (coalesced LDS stage) + fused dt_proj -> y_bf
    scansplit_k<<<dim3(kDI / 4, kB), 256, 0, stream>>>(
        projT, uT_bf, sgT_bf, dtproj_w + (size_t)layer * kDI * kDTR,
        dtproj_b + layer * kDI, A_log + (size_t)layer * kDI * kDS,
        Dskip + layer * kDI, y_bf);
    // out_proj (MFMA, split-K=4, atomic into residual): tok += y x W^T
    bgemm_out_k<<<dim3(3, 16, 4), 256, 0, stream>>>(
        y_bf, kDI, wl + kWIN, kDI, tok, kDM, kDI / 4);
  }

  // final LN + fused mean-pool (atomicAdd into pre-zeroed pooled)
  lnpool_k<<<kTok, kDM, 0, stream>>>(tok, pooled, fn_g, fn_b);
  head_k<<<kB * 4, 64, 0, stream>>>(pooled, head_w, head_b, out);
}

// Round 9
// 1170.584 us; speedup vs baseline: 3.0862x; 1.0049x over previous
//
#include <hip/hip_runtime.h>
#include <math.h>

namespace {

constexpr int kB   = 8;
constexpr int kL   = 256;
constexpr int kTok = 2048;   // B*L
constexpr int kDM  = 384;
constexpr int kDI  = 768;
constexpr int kDS  = 16;
constexpr int kDTR = 24;
constexpr int kPROJ = 56;    // DTR + 2*DS
constexpr int kNL  = 12;

constexpr int kWIN  = 2 * kDI * kDM;   // 589824 in_proj weights/layer
constexpr int kWOUT = kDM * kDI;       // 294912
constexpr int kWX   = kPROJ * kDI;     // 43008
constexpr int kWTOT = kWIN + kWOUT + kWX;  // 927744

typedef float f32x4 __attribute__((ext_vector_type(4)));
typedef short short8 __attribute__((ext_vector_type(8)));

__device__ __forceinline__ float softplus_f(float x) {
  return (x > 20.f) ? x : log1pf(__expf(x));
}
__device__ __forceinline__ float silu_f(float x) {
  return x / (1.f + __expf(-x));
}
__device__ __forceinline__ unsigned short f2bf(float f) {
  union { float f; unsigned u; } v; v.f = f;
  unsigned r = v.u + 0x7FFFu + ((v.u >> 16) & 1u);
  return (unsigned short)(r >> 16);
}
__device__ __forceinline__ float bf2f(unsigned short u) {
  return __uint_as_float((unsigned)u << 16);
}

// ------------- patch embed GEMM: tok = im2col(x)·patch_w^T + b + pos -------
__global__ __launch_bounds__(256) void patch_gemm_k(
    const float* __restrict__ x, const float* __restrict__ Bw,
    const float* __restrict__ bias, const float* __restrict__ pos,
    float* __restrict__ C) {
  __shared__ float As[16][68];
  __shared__ float Bs[16][68];
  int tid = threadIdx.x;
  int bm = blockIdx.y * 64;
  int bn = blockIdx.x * 64;
  int lr = tid >> 2;
  int lk = (tid & 3) << 2;
  int tm = (tid >> 4) << 2;
  int tn = (tid & 15) << 2;
  float acc[4][4] = {};
  for (int k0 = 0; k0 < 256; k0 += 16) {
    {
      int token = bm + lr;
      int b = token >> 8, l = token & 255;
      int h = l >> 3, w = l & 7;
      int p = k0 >> 4;
      const float* ap = x + ((size_t)(b * 512) + h * 16 + p) * 128 + w * 16 + lk;
      float4 av = *(const float4*)ap;
      As[lk + 0][lr] = av.x; As[lk + 1][lr] = av.y;
      As[lk + 2][lr] = av.z; As[lk + 3][lr] = av.w;
    }
    {
      const float* bp = Bw + (size_t)(bn + lr) * 256 + k0 + lk;
      float4 bv = *(const float4*)bp;
      Bs[lk + 0][lr] = bv.x; Bs[lk + 1][lr] = bv.y;
      Bs[lk + 2][lr] = bv.z; Bs[lk + 3][lr] = bv.w;
    }
    __syncthreads();
    #pragma unroll
    for (int k = 0; k < 16; ++k) {
      float4 a = *(const float4*)&As[k][tm];
      float4 b = *(const float4*)&Bs[k][tn];
      float av[4] = {a.x, a.y, a.z, a.w};
      float bv[4] = {b.x, b.y, b.z, b.w};
      #pragma unroll
      for (int i = 0; i < 4; ++i)
        #pragma unroll
        for (int j = 0; j < 4; ++j)
          acc[i][j] = fmaf(av[i], bv[j], acc[i][j]);
    }
    __syncthreads();
  }
  #pragma unroll
  for (int i = 0; i < 4; ++i) {
    int row = bm + tm + i;
    #pragma unroll
    for (int j = 0; j < 4; ++j) {
      int col = bn + tn + j;
      C[(size_t)row * kDM + col] =
          acc[i][j] + bias[col] + pos[(size_t)(row & 255) * kDM + col];
    }
  }
}

// ------------- final layernorm + fused mean-pool + head (atomic to out) ----
// out[b][c] = sum_t sum_d LN(tok[t])[d]*hw[c][d]/256 + hb[c]; out pre-zeroed
// by the harness, so each token-block atomicAdds its 4 partial dots.
__global__ __launch_bounds__(384) void lnpool_head_k(
    const float* __restrict__ in, const float* __restrict__ g,
    const float* __restrict__ bb, const float* __restrict__ hw,
    const float* __restrict__ hb, float* __restrict__ out) {
  int t = blockIdx.x, d = threadIdx.x;
  float v = in[(size_t)t * kDM + d];
  float s = v, s2 = v * v;
  #pragma unroll
  for (int m = 32; m >= 1; m >>= 1) {
    s  += __shfl_xor(s, m);
    s2 += __shfl_xor(s2, m);
  }
  __shared__ float ps[6], ps2[6];
  __shared__ float pc[6][4];
  int wv = d >> 6;
  if ((d & 63) == 0) { ps[wv] = s; ps2[wv] = s2; }
  __syncthreads();
  float S = 0.f, S2 = 0.f;
  #pragma unroll
  for (int i = 0; i < 6; ++i) { S += ps[i]; S2 += ps2[i]; }
  float mean = S * (1.f / 384.f);
  float var  = S2 * (1.f / 384.f) - mean * mean;
  float r = rsqrtf(var + 1e-5f);
  float o = (v - mean) * r * g[d] + bb[d];
  // per-class partial dots, wave-reduced then LDS-reduced
  float p[4];
  #pragma unroll
  for (int c = 0; c < 4; ++c) p[c] = o * hw[(size_t)c * kDM + d];
  #pragma unroll
  for (int m = 32; m >= 1; m >>= 1) {
    #pragma unroll
    for (int c = 0; c < 4; ++c) p[c] += __shfl_xor(p[c], m);
  }
  if ((d & 63) == 0) {
    #pragma unroll
    for (int c = 0; c < 4; ++c) pc[wv][c] = p[c];
  }
  __syncthreads();
  if (d < 4) {
    float acc = 0.f;
    #pragma unroll
    for (int i = 0; i < 6; ++i) acc += pc[i][d];
    acc *= (1.f / 256.f);
    if ((t & 255) == 0) acc += hb[d];   // hb added once per batch
    atomicAdd(&out[(size_t)(t >> 8) * 4 + d], acc);
  }
}

// ------------- convert ALL layers' GEMM weights fp32 -> bf16 ---------------
__global__ __launch_bounds__(256) void convert_all_k(
    const float* __restrict__ w_in, const float* __restrict__ w_out,
    const float* __restrict__ w_x, unsigned short* __restrict__ dst) {
  int layer = blockIdx.y;
  int tid = threadIdx.x;
  int i4 = (blockIdx.x * 256 + tid) * 4;
  if (i4 >= kWTOT) return;
  const float* src;
  int off;
  if (i4 < kWIN) { src = w_in + (size_t)layer * kWIN; off = i4; }
  else if (i4 < kWIN + kWOUT) { src = w_out + (size_t)layer * kWOUT; off = i4 - kWIN; }
  else { src = w_x + (size_t)layer * kWX; off = i4 - kWIN - kWOUT; }
  float4 v = *(const float4*)(src + off);
  unsigned short o[4] = {f2bf(v.x), f2bf(v.y), f2bf(v.z), f2bf(v.w)};
  *(uint2*)(dst + (size_t)layer * kWTOT + i4) = *(const uint2*)o;
}

// ------------- in_proj with fused LayerNorm (+ proj zeroing), 64x128 -------
// xz_bf[2048,1536] = LN(tok)[2048,384] · W[1536,384]^T  (bf16 MFMA, bf16 out)
// grid (12, 32) = 384 blocks.
__global__ __launch_bounds__(256) void inproj_ln_k(
    const float* __restrict__ tok, const unsigned short* __restrict__ Bw,
    const float* __restrict__ g, const float* __restrict__ bb,
    unsigned short* __restrict__ Cbf, float* __restrict__ proj_zero) {
  __shared__ __align__(16) unsigned short As[4][64][8];
  __shared__ __align__(16) unsigned short Bs[4][128][8];
  __shared__ float smean[64], srstd[64];
  __shared__ float sg_[kDM], sb_[kDM];
  int tid = threadIdx.x;
  int bm = blockIdx.y * 64;
  int bn = blockIdx.x * 128;
  // proj zeroing for the upcoming split-K atomics (384 blocks cover it)
  {
    int bid = blockIdx.y * 12 + blockIdx.x;
    for (int i = bid * 256 + tid; i < kTok * kPROJ; i += 384 * 256)
      proj_zero[i] = 0.f;
  }
  for (int i = tid; i < kDM; i += 256) { sg_[i] = g[i]; sb_[i] = bb[i]; }
  // LN stats prepass: 4 threads per row
  {
    int r = tid >> 2, quarter = tid & 3;
    const float* rp = tok + (size_t)(bm + r) * kDM + quarter * 96;
    float s = 0.f, s2 = 0.f;
    #pragma unroll
    for (int q = 0; q < 24; ++q) {
      float4 v = ((const float4*)rp)[q];
      s  += v.x + v.y + v.z + v.w;
      s2 += v.x * v.x + v.y * v.y + v.z * v.z + v.w * v.w;
    }
    s  += __shfl_xor(s, 1);  s2 += __shfl_xor(s2, 1);
    s  += __shfl_xor(s, 2);  s2 += __shfl_xor(s2, 2);
    if (quarter == 0) {
      float mean = s * (1.f / 384.f);
      float var  = s2 * (1.f / 384.f) - mean * mean;
      smean[r] = mean;
      srstd[r] = rsqrtf(var + 1e-5f);
    }
  }
  __syncthreads();
  int wave = tid >> 6, lane = tid & 63;
  int lm = lane & 15, lq = lane >> 4;
  int wm = (wave & 1) * 32, wn = (wave >> 1) * 64;
  f32x4 acc[2][4] = {};
  for (int k0 = 0; k0 < kDM; k0 += 32) {
    int ar = tid & 63, aq = tid >> 6;  // aq 0..3 (k-quad)
    unsigned short av[8];
    {
      float mean = smean[ar], rstd = srstd[ar];
      const float* ap = tok + (size_t)(bm + ar) * kDM + k0 + aq * 8;
      float4 v0 = ((const float4*)ap)[0];
      float4 v1 = ((const float4*)ap)[1];
      float vv[8] = {v0.x, v0.y, v0.z, v0.w, v1.x, v1.y, v1.z, v1.w};
      #pragma unroll
      for (int j = 0; j < 8; ++j) {
        int k = k0 + aq * 8 + j;
        av[j] = f2bf((vv[j] - mean) * rstd * sg_[k] + sb_[k]);
      }
    }
    int br = tid & 127, bq0 = tid >> 7, bq1 = bq0 + 2;
    uint4 b0 = *(const uint4*)(Bw + (size_t)(bn + br) * kDM + k0 + bq0 * 8);
    uint4 b1 = *(const uint4*)(Bw + (size_t)(bn + br) * kDM + k0 + bq1 * 8);
    __syncthreads();
    *(uint4*)&As[aq][ar][0]  = *(const uint4*)av;
    *(uint4*)&Bs[bq0][br][0] = b0;
    *(uint4*)&Bs[bq1][br][0] = b1;
    __syncthreads();
    short8 bfrag[4];
    #pragma unroll
    for (int ni = 0; ni < 4; ++ni)
      bfrag[ni] = *(const short8*)&Bs[lq][wn + ni * 16 + lm][0];
    #pragma unroll
    for (int mi = 0; mi < 2; ++mi) {
      short8 afrag = *(const short8*)&As[lq][wm + mi * 16 + lm][0];
      #pragma unroll
      for (int ni = 0; ni < 4; ++ni)
        acc[mi][ni] = __builtin_amdgcn_mfma_f32_16x16x32_bf16(
            afrag, bfrag[ni], acc[mi][ni], 0, 0, 0);
    }
  }
  #pragma unroll
  for (int mi = 0; mi < 2; ++mi) {
    #pragma unroll
    for (int ni = 0; ni < 4; ++ni) {
      int grow0 = bm + wm + mi * 16 + lq * 4;
      int gcol = bn + wn + ni * 16 + lm;
      #pragma unroll
      for (int r = 0; r < 4; ++r)
        Cbf[(size_t)(grow0 + r) * (2 * kDI) + gcol] = f2bf(acc[mi][ni][r]);
    }
  }
}

// ------------- x_proj with fused depthwise conv + SiLU + z-gate ------------
// grid (32, 6) = 192 blocks. Side outputs: uT_bf[b][d][l] and
// sgT_bf[b][d][l] = silu(z) (both bf16, lane-contiguous along l).
__global__ __launch_bounds__(256) void xproj_conv_k(
    const unsigned short* __restrict__ xz, const unsigned short* __restrict__ Bw,
    const float* __restrict__ cw, const float* __restrict__ cb,
    float* __restrict__ proj, unsigned short* __restrict__ uT_bf,
    unsigned short* __restrict__ sgT_bf) {
  __shared__ __align__(16) unsigned short As[4][64][8];
  __shared__ __align__(16) unsigned short Bs[4][64][8];
  __shared__ float scw[128][4];
  __shared__ float scb[128];
  int tid = threadIdx.x;
  int bm = blockIdx.x * 64;       // token tile
  int kbase = blockIdx.y * 128;   // d chunk (split-K = 6)
  int wave = tid >> 6, lane = tid & 63;
  int lm = lane & 15, lq = lane >> 4;
  int wm = wave * 16;
  f32x4 acc[4] = {};

  if (tid < 128) {
    *(float4*)&scw[tid][0] = *(const float4*)(cw + (size_t)(kbase + tid) * 4);
    scb[tid] = cb[kbase + tid];
  }
  __syncthreads();

  int ar = tid & 63;
  int aq = tid >> 6;   // 0..3
  int t = bm + ar;
  int b = t >> 8, l = t & 255;

  for (int kt = 0; kt < 4; ++kt) {
    int k0 = kbase + kt * 32;
    int dloc = kt * 32 + aq * 8;
    int dg = kbase + dloc;
    unsigned short av[8];
    {
      float vals[4][8];
      #pragma unroll
      for (int q = 0; q < 4; ++q) {
        if (l - 3 + q >= 0) {
          uint4 r = *(const uint4*)(xz + (size_t)(t - 3 + q) * (2 * kDI) + dg);
          const unsigned short* rs = (const unsigned short*)&r;
          #pragma unroll
          for (int j = 0; j < 8; ++j) vals[q][j] = bf2f(rs[j]);
        } else {
          #pragma unroll
          for (int j = 0; j < 8; ++j) vals[q][j] = 0.f;
        }
      }
      // z-gate for the same 8 channels (row t, offset +768)
      uint4 zr = *(const uint4*)(xz + (size_t)t * (2 * kDI) + kDI + dg);
      const unsigned short* zs = (const unsigned short*)&zr;
      #pragma unroll
      for (int j = 0; j < 8; ++j) {
        float a = scb[dloc + j];
        a = fmaf(vals[0][j], scw[dloc + j][0], a);
        a = fmaf(vals[1][j], scw[dloc + j][1], a);
        a = fmaf(vals[2][j], scw[dloc + j][2], a);
        a = fmaf(vals[3][j], scw[dloc + j][3], a);
        unsigned short ub = f2bf(silu_f(a));
        av[j] = ub;
        size_t rbase = ((size_t)b * kDI + dg + j) * kL + l;
        uT_bf[rbase] = ub;
        sgT_bf[rbase] = f2bf(silu_f(bf2f(zs[j])));
      }
    }
    int br = tid & 63, bq = tid >> 6;
    uint4 b0;
    if (br < kPROJ)
      b0 = *(const uint4*)(Bw + (size_t)br * kDI + k0 + bq * 8);
    else
      b0 = make_uint4(0u, 0u, 0u, 0u);
    __syncthreads();
    *(uint4*)&As[aq][ar][0] = *(const uint4*)av;
    *(uint4*)&Bs[bq][br][0] = b0;
    __syncthreads();
    short8 afrag = *(const short8*)&As[lq][wm + lm][0];
    #pragma unroll
    for (int ni = 0; ni < 4; ++ni) {
      short8 bfrag = *(const short8*)&Bs[lq][ni * 16 + lm][0];
      acc[ni] = __builtin_amdgcn_mfma_f32_16x16x32_bf16(
          afrag, bfrag, acc[ni], 0, 0, 0);
    }
  }

  #pragma unroll
  for (int ni = 0; ni < 4; ++ni) {
    int grow0 = bm + wm + lq * 4;
    int gcol = ni * 16 + lm;
    if (gcol < kPROJ) {
      #pragma unroll
      for (int r = 0; r < 4; ++r)
        atomicAdd(&proj[(size_t)(grow0 + r) * kPROJ + gcol], acc[ni][r]);
    }
  }
}

// ------------- bf16 MFMA NT GEMM (out_proj): atomicAdd into residual -------
// 64x64 tiles: grid (6, 32, 4) = 768 blocks (3/CU). Wave = 32x32 quadrant.
__global__ __launch_bounds__(256) void bgemm_out_k(
    const unsigned short* __restrict__ A, int lda,
    const unsigned short* __restrict__ B, int ldb,
    float* __restrict__ C, int ldc, int Kc) {
  __shared__ __align__(16) unsigned short As[4][64][8];
  __shared__ __align__(16) unsigned short Bs[4][64][8];
  int tid = threadIdx.x;
  int bm = blockIdx.y * 64;
  int bn = blockIdx.x * 64;
  int k_begin = blockIdx.z * Kc;
  int wave = tid >> 6, lane = tid & 63;
  int lm = lane & 15, lq = lane >> 4;
  int wm = (wave & 1) * 32, wn = (wave >> 1) * 32;
  f32x4 acc[2][2] = {};

  for (int kt = 0; kt < Kc; kt += 32) {
    int k0 = k_begin + kt;
    int ar = tid & 63, aq = tid >> 6;
    uint4 a0 = *(const uint4*)(A + (size_t)(bm + ar) * lda + k0 + aq * 8);
    uint4 b0 = *(const uint4*)(B + (size_t)(bn + ar) * ldb + k0 + aq * 8);
    __syncthreads();
    *(uint4*)&As[aq][ar][0] = a0;
    *(uint4*)&Bs[aq][ar][0] = b0;
    __syncthreads();
    short8 bfrag[2];
    #pragma unroll
    for (int ni = 0; ni < 2; ++ni)
      bfrag[ni] = *(const short8*)&Bs[lq][wn + ni * 16 + lm][0];
    #pragma unroll
    for (int mi = 0; mi < 2; ++mi) {
      short8 afrag = *(const short8*)&As[lq][wm + mi * 16 + lm][0];
      #pragma unroll
      for (int ni = 0; ni < 2; ++ni)
        acc[mi][ni] = __builtin_amdgcn_mfma_f32_16x16x32_bf16(
            afrag, bfrag[ni], acc[mi][ni], 0, 0, 0);
    }
  }

  #pragma unroll
  for (int mi = 0; mi < 2; ++mi) {
    #pragma unroll
    for (int ni = 0; ni < 2; ++ni) {
      int grow0 = bm + wm + mi * 16 + lq * 4;
      int gcol = bn + wn + ni * 16 + lm;
      #pragma unroll
      for (int r = 0; r < 4; ++r)
        atomicAdd(&C[(size_t)(grow0 + r) * ldc + gcol], acc[mi][ni][r]);
    }
  }
}

// ------------- split-state scan + fused dt_proj (LDS-staged proj) ----------
// Two-phase reuse of one [256][33] buffer: cols 0..23 for dt_proj, then
// cols 24..55 for the B/C scan reads. All per-token reads are LDS.
__global__ __launch_bounds__(256, 3) void scansplit_k(
    const float* __restrict__ proj, const unsigned short* __restrict__ uT_bf,
    const unsigned short* __restrict__ sgT_bf, const float* __restrict__ dtw,
    const float* __restrict__ dtb, const float* __restrict__ A_log,
    const float* __restrict__ Dsk, unsigned short* __restrict__ y_bf) {
  int d0 = blockIdx.x * 4;
  int b = blockIdx.y;
  int tid = threadIdx.x;
  int dsub = tid & 3;
  int nq = (tid >> 2) & 3;   // state quarter: states nq*4 .. nq*4+3
  int c = tid >> 4;          // chunk of 16 tokens
  int d = d0 + dsub;
  __shared__ float sproj[256][33];   // stride 33: 2-way banks (free)
  __shared__ float sdt[16][16][5];   // [chunk][token-in-chunk][dsub]
  __shared__ float sh[16][16][5];    // [chunk][state][dsub]
  __shared__ float sca[16][16][5];

  const float* pr0 = proj + (size_t)(b * kL) * kPROJ;

  // stage A: proj cols 0..23 (dt_proj inputs) -> sproj[tok][0..23]
  {
    const float* rp = pr0 + (size_t)tid * kPROJ;
    #pragma unroll
    for (int q = 0; q < 6; ++q) {
      float4 v = ((const float4*)rp)[q];
      sproj[tid][q * 4 + 0] = v.x;
      sproj[tid][q * 4 + 1] = v.y;
      sproj[tid][q * 4 + 2] = v.z;
      sproj[tid][q * 4 + 3] = v.w;
    }
  }

  // A (pre-scaled by log2(e) so the scan uses exp2 directly)
  float Av2[4];
  {
    const float kLog2e = 1.44269504088896340736f;
    float4 v = *(const float4*)(A_log + (size_t)d * kDS + nq * 4);
    Av2[0] = -__expf(v.x) * kLog2e;
    Av2[1] = -__expf(v.y) * kLog2e;
    Av2[2] = -__expf(v.z) * kLog2e;
    Av2[3] = -__expf(v.w) * kLog2e;
  }
  float bdt = dtb[d];
  float Dv = Dsk[d];

  float wdt[24];
  {
    const float* wp = dtw + (size_t)d * kDTR;
    #pragma unroll
    for (int q = 0; q < 6; ++q) {
      float4 v = ((const float4*)wp)[q];
      wdt[q * 4 + 0] = v.x; wdt[q * 4 + 1] = v.y;
      wdt[q * 4 + 2] = v.z; wdt[q * 4 + 3] = v.w;
    }
  }

  // u: 16 bf16 tokens packed in 2 uint4, unpacked per use
  union { uint4 v[2]; unsigned short s[16]; } uu;
  {
    const unsigned short* up = uT_bf + ((size_t)b * kDI + d) * kL + c * 16;
    uu.v[0] = ((const uint4*)up)[0];
    uu.v[1] = ((const uint4*)up)[1];
  }

  __syncthreads();   // stage A visible

  // dt_proj for my 4 tokens (l = c*16 + nq*4 + i) from LDS -> sdt
  #pragma unroll
  for (int i = 0; i < 4; ++i) {
    int tok = c * 16 + nq * 4 + i;
    float acc = bdt;
    #pragma unroll
    for (int r = 0; r < 24; ++r) acc = fmaf(sproj[tok][r], wdt[r], acc);
    sdt[c][nq * 4 + i][dsub] = softplus_f(acc);
  }
  __syncthreads();   // dt reads of sproj done; sdt written

  // stage B: proj cols 24..55 (B at 0..15, C at 16..31) -> sproj[tok][0..31]
  {
    const float* rp = pr0 + (size_t)tid * kPROJ + 24;
    #pragma unroll
    for (int q = 0; q < 8; ++q) {
      float4 v = ((const float4*)rp)[q];
      sproj[tid][q * 4 + 0] = v.x;
      sproj[tid][q * 4 + 1] = v.y;
      sproj[tid][q * 4 + 2] = v.z;
      sproj[tid][q * 4 + 3] = v.w;
    }
  }
  __syncthreads();   // stage B visible

  // pass 1: local chunk scan over my 4 states (all operands LDS/regs)
  float h[4] = {};
  float S = 0.f;
  #pragma unroll
  for (int i = 0; i < 16; ++i) {
    int tok = c * 16 + i;
    float dl = sdt[c][i][dsub];
    float du = dl * bf2f(uu.s[i]);
    S += dl;
    #pragma unroll
    for (int n = 0; n < 4; ++n) {
      float a = exp2f(dl * Av2[n]);
      h[n] = fmaf(a, h[n], du * sproj[tok][nq * 4 + n]);
    }
  }
  {
    int nrow = nq * 4;
    #pragma unroll
    for (int n = 0; n < 4; ++n) {
      sh[c][nrow + n][dsub] = h[n];
      sca[c][nrow + n][dsub] = exp2f(S * Av2[n]);  // == prod of a's
    }
  }
  __syncthreads();

  // chunk-prefix combine (same address across the wave -> LDS broadcast)
  float h0[4] = {};
  {
    int nrow = nq * 4;
    for (int j = 0; j < c; ++j) {
      #pragma unroll
      for (int n = 0; n < 4; ++n)
        h0[n] = fmaf(sca[j][nrow + n][dsub], h0[n], sh[j][nrow + n][dsub]);
    }
  }

  // z-gate for nq==0 quarter: packed bf16
  union { uint4 v[2]; unsigned short s[16]; } zz;
  zz.v[0] = make_uint4(0u, 0u, 0u, 0u);
  zz.v[1] = make_uint4(0u, 0u, 0u, 0u);
  if (nq == 0) {
    const unsigned short* sp = sgT_bf + ((size_t)b * kDI + d) * kL + c * 16;
    zz.v[0] = ((const uint4*)sp)[0];
    zz.v[1] = ((const uint4*)sp)[1];
  }

  // pass 2: true scan from h0; partial y over my 4 states; 2 shuffles; store
  unsigned short* yp = y_bf + (size_t)(b * kL + c * 16) * kDI + d;
  #pragma unroll
  for (int i = 0; i < 16; ++i) {
    int tok = c * 16 + i;
    float dl = sdt[c][i][dsub];
    float uv = bf2f(uu.s[i]);
    float du = dl * uv;
    float yv = 0.f;
    #pragma unroll
    for (int n = 0; n < 4; ++n) {
      float a = exp2f(dl * Av2[n]);
      h0[n] = fmaf(a, h0[n], du * sproj[tok][nq * 4 + n]);
      yv = fmaf(h0[n], sproj[tok][16 + nq * 4 + n], yv);
    }
    yv += __shfl_xor(yv, 4);
    yv += __shfl_xor(yv, 8);
    if (nq == 0) yp[(size_t)i * kDI] = f2bf((yv + uv * Dv) * bf2f(zz.s[i]));
  }
}

}  // namespace

extern "C" void kernel_launch(void* const* d_in, const int* in_sizes, int n_in,
                              void* d_out, int out_size, void* d_ws, size_t ws_size,
                              hipStream_t stream) {
  (void)in_sizes; (void)n_in; (void)out_size; (void)ws_size;
  const float* x        = (const float*)d_in[0];
  const float* patch_w  = (const float*)d_in[1];
  const float* patch_b  = (const float*)d_in[2];
  const float* pos      = (const float*)d_in[3];
  const float* ln_g     = (const float*)d_in[4];
  const float* ln_b     = (const float*)d_in[5];
  const float* in_w     = (const float*)d_in[6];
  const float* conv_w   = (const float*)d_in[7];
  const float* conv_b   = (const float*)d_in[8];
  const float* xproj_w  = (const float*)d_in[9];
  const float* dtproj_w = (const float*)d_in[10];
  const float* dtproj_b = (const float*)d_in[11];
  const float* A_log    = (const float*)d_in[12];
  const float* Dskip    = (const float*)d_in[13];
  const float* out_w    = (const float*)d_in[14];
  const float* fn_g     = (const float*)d_in[15];
  const float* fn_b     = (const float*)d_in[16];
  const float* head_w   = (const float*)d_in[17];
  const float* head_b   = (const float*)d_in[18];
  float* out = (float*)d_out;

  float* ws = (float*)d_ws;
  float* tok    = ws; ws += kTok * kDM;       // fp32 residual
  float* proj   = ws; ws += kTok * kPROJ;     // [t][56] row-major
  unsigned short* xz_bf  = (unsigned short*)ws; ws += kTok * 2 * kDI / 2;
  unsigned short* uT_bf  = (unsigned short*)ws; ws += kTok * kDI / 2;
  unsigned short* sgT_bf = (unsigned short*)ws; ws += kTok * kDI / 2;
  unsigned short* y_bf   = (unsigned short*)ws; ws += kTok * kDI / 2;
  unsigned short* w_bf   = (unsigned short*)ws; ws += (size_t)kNL * kWTOT / 2;

  // all-layer weight cast (once per call)
  convert_all_k<<<dim3(kWTOT / 4 / 256, kNL), 256, 0, stream>>>(
      in_w, out_w, xproj_w, w_bf);

  // Patch embedding fused: im2col + GEMM + bias + pos
  patch_gemm_k<<<dim3(6, 32), 256, 0, stream>>>(x, patch_w, patch_b, pos, tok);

  for (int layer = 0; layer < kNL; ++layer) {
    const unsigned short* wl = w_bf + (size_t)layer * kWTOT;
    // in_proj with fused LN (+ proj zero): LN(tok) x W^T -> xz_bf  (384 blk)
    inproj_ln_k<<<dim3(12, 32), 256, 0, stream>>>(
        tok, wl, ln_g + layer * kDM, ln_b + layer * kDM, xz_bf, proj);
    // x_proj with fused conv+SiLU+z-gate: proj += u·Wx^T ; uT_bf, sgT_bf
    xproj_conv_k<<<dim3(32, 6), 256, 0, stream>>>(
        xz_bf, wl + kWIN + kWOUT, conv_w + layer * kDI * 4,
        conv_b + layer * kDI, proj, uT_bf, sgT_bf);
    // split-state register scan + fused dt_proj -> y_bf (1536 blk)
    scansplit_k<<<dim3(kDI / 4, kB), 256, 0, stream>>>(
        proj, uT_bf, sgT_bf, dtproj_w + (size_t)layer * kDI * kDTR,
        dtproj_b + layer * kDI, A_log + (size_t)layer * kDI * kDS,
        Dskip + layer * kDI, y_bf);
    // out_proj (MFMA, 64x64 tiles, split-K=4, atomic into residual)
    bgemm_out_k<<<dim3(6, 32, 4), 256, 0, stream>>>(
        y_bf, kDI, wl + kWIN, kDI, tok, kDM, kDI / 4);
  }

  // final LN + mean-pool + head fused (atomicAdd into harness-zeroed out)
  lnpool_head_k<<<kTok, kDM, 0, stream>>>(tok, fn_g, fn_b, head_w, head_b, out);
}

// Round 12
// 1126.382 us; speedup vs baseline: 3.2073x; 1.0392x over previous
//
#include <hip/hip_runtime.h>
#include <math.h>

namespace {

constexpr int kB   = 8;
constexpr int kL   = 256;
constexpr int kTok = 2048;   // B*L
constexpr int kDM  = 384;
constexpr int kDI  = 768;
constexpr int kDS  = 16;
constexpr int kDTR = 24;
constexpr int kPROJ = 56;    // DTR + 2*DS
constexpr int kNL  = 12;

constexpr int kWIN  = 2 * kDI * kDM;   // 589824 in_proj weights/layer
constexpr int kWOUT = kDM * kDI;       // 294912
constexpr int kWX   = kPROJ * kDI;     // 43008
constexpr int kWTOT = kWIN + kWOUT + kWX;  // 927744

typedef float f32x4 __attribute__((ext_vector_type(4)));
typedef short short8 __attribute__((ext_vector_type(8)));

__device__ __forceinline__ float softplus_f(float x) {
  return (x > 20.f) ? x : log1pf(__expf(x));
}
__device__ __forceinline__ float silu_f(float x) {
  return x / (1.f + __expf(-x));
}
__device__ __forceinline__ unsigned short f2bf(float f) {
  union { float f; unsigned u; } v; v.f = f;
  unsigned r = v.u + 0x7FFFu + ((v.u >> 16) & 1u);
  return (unsigned short)(r >> 16);
}
__device__ __forceinline__ float bf2f(unsigned short u) {
  return __uint_as_float((unsigned)u << 16);
}

// ------------- patch embed GEMM: tok = im2col(x)·patch_w^T + b + pos -------
__global__ __launch_bounds__(256) void patch_gemm_k(
    const float* __restrict__ x, const float* __restrict__ Bw,
    const float* __restrict__ bias, const float* __restrict__ pos,
    float* __restrict__ C) {
  __shared__ float As[16][68];
  __shared__ float Bs[16][68];
  int tid = threadIdx.x;
  int bm = blockIdx.y * 64;
  int bn = blockIdx.x * 64;
  int lr = tid >> 2;
  int lk = (tid & 3) << 2;
  int tm = (tid >> 4) << 2;
  int tn = (tid & 15) << 2;
  float acc[4][4] = {};
  for (int k0 = 0; k0 < 256; k0 += 16) {
    {
      int token = bm + lr;
      int b = token >> 8, l = token & 255;
      int h = l >> 3, w = l & 7;
      int p = k0 >> 4;
      const float* ap = x + ((size_t)(b * 512) + h * 16 + p) * 128 + w * 16 + lk;
      float4 av = *(const float4*)ap;
      As[lk + 0][lr] = av.x; As[lk + 1][lr] = av.y;
      As[lk + 2][lr] = av.z; As[lk + 3][lr] = av.w;
    }
    {
      const float* bp = Bw + (size_t)(bn + lr) * 256 + k0 + lk;
      float4 bv = *(const float4*)bp;
      Bs[lk + 0][lr] = bv.x; Bs[lk + 1][lr] = bv.y;
      Bs[lk + 2][lr] = bv.z; Bs[lk + 3][lr] = bv.w;
    }
    __syncthreads();
    #pragma unroll
    for (int k = 0; k < 16; ++k) {
      float4 a = *(const float4*)&As[k][tm];
      float4 b = *(const float4*)&Bs[k][tn];
      float av[4] = {a.x, a.y, a.z, a.w};
      float bv[4] = {b.x, b.y, b.z, b.w};
      #pragma unroll
      for (int i = 0; i < 4; ++i)
        #pragma unroll
        for (int j = 0; j < 4; ++j)
          acc[i][j] = fmaf(av[i], bv[j], acc[i][j]);
    }
    __syncthreads();
  }
  #pragma unroll
  for (int i = 0; i < 4; ++i) {
    int row = bm + tm + i;
    #pragma unroll
    for (int j = 0; j < 4; ++j) {
      int col = bn + tn + j;
      C[(size_t)row * kDM + col] =
          acc[i][j] + bias[col] + pos[(size_t)(row & 255) * kDM + col];
    }
  }
}

// ------------- final layernorm + fused mean-pool + head (atomic to out) ----
__global__ __launch_bounds__(384) void lnpool_head_k(
    const float* __restrict__ in, const float* __restrict__ g,
    const float* __restrict__ bb, const float* __restrict__ hw,
    const float* __restrict__ hb, float* __restrict__ out) {
  int t = blockIdx.x, d = threadIdx.x;
  float v = in[(size_t)t * kDM + d];
  float s = v, s2 = v * v;
  #pragma unroll
  for (int m = 32; m >= 1; m >>= 1) {
    s  += __shfl_xor(s, m);
    s2 += __shfl_xor(s2, m);
  }
  __shared__ float ps[6], ps2[6];
  __shared__ float pc[6][4];
  int wv = d >> 6;
  if ((d & 63) == 0) { ps[wv] = s; ps2[wv] = s2; }
  __syncthreads();
  float S = 0.f, S2 = 0.f;
  #pragma unroll
  for (int i = 0; i < 6; ++i) { S += ps[i]; S2 += ps2[i]; }
  float mean = S * (1.f / 384.f);
  float var  = S2 * (1.f / 384.f) - mean * mean;
  float r = rsqrtf(var + 1e-5f);
  float o = (v - mean) * r * g[d] + bb[d];
  float p[4];
  #pragma unroll
  for (int c = 0; c < 4; ++c) p[c] = o * hw[(size_t)c * kDM + d];
  #pragma unroll
  for (int m = 32; m >= 1; m >>= 1) {
    #pragma unroll
    for (int c = 0; c < 4; ++c) p[c] += __shfl_xor(p[c], m);
  }
  if ((d & 63) == 0) {
    #pragma unroll
    for (int c = 0; c < 4; ++c) pc[wv][c] = p[c];
  }
  __syncthreads();
  if (d < 4) {
    float acc = 0.f;
    #pragma unroll
    for (int i = 0; i < 6; ++i) acc += pc[i][d];
    acc *= (1.f / 256.f);
    if ((t & 255) == 0) acc += hb[d];   // hb added once per batch
    atomicAdd(&out[(size_t)(t >> 8) * 4 + d], acc);
  }
}

// ------------- convert ALL layers' GEMM weights fp32 -> bf16 ---------------
__global__ __launch_bounds__(256) void convert_all_k(
    const float* __restrict__ w_in, const float* __restrict__ w_out,
    const float* __restrict__ w_x, unsigned short* __restrict__ dst) {
  int layer = blockIdx.y;
  int tid = threadIdx.x;
  int i4 = (blockIdx.x * 256 + tid) * 4;
  if (i4 >= kWTOT) return;
  const float* src;
  int off;
  if (i4 < kWIN) { src = w_in + (size_t)layer * kWIN; off = i4; }
  else if (i4 < kWIN + kWOUT) { src = w_out + (size_t)layer * kWOUT; off = i4 - kWIN; }
  else { src = w_x + (size_t)layer * kWX; off = i4 - kWIN - kWOUT; }
  float4 v = *(const float4*)(src + off);
  unsigned short o[4] = {f2bf(v.x), f2bf(v.y), f2bf(v.z), f2bf(v.w)};
  *(uint2*)(dst + (size_t)layer * kWTOT + i4) = *(const uint2*)o;
}

// ------------- in_proj with fused LayerNorm (+ proj zeroing), 64x128 -------
// xz_bf[2048,1536] = LN(tok)[2048,384] · W[1536,384]^T  (bf16 MFMA, bf16 out)
// grid (12, 32) = 384 blocks.
__global__ __launch_bounds__(256) void inproj_ln_k(
    const float* __restrict__ tok, const unsigned short* __restrict__ Bw,
    const float* __restrict__ g, const float* __restrict__ bb,
    unsigned short* __restrict__ Cbf, float* __restrict__ proj_zero) {
  __shared__ __align__(16) unsigned short As[4][64][8];
  __shared__ __align__(16) unsigned short Bs[4][128][8];
  __shared__ float smean[64], srstd[64];
  __shared__ float sg_[kDM], sb_[kDM];
  int tid = threadIdx.x;
  int bm = blockIdx.y * 64;
  int bn = blockIdx.x * 128;
  // proj zeroing for the upcoming split-K atomics (384 blocks cover it)
  {
    int bid = blockIdx.y * 12 + blockIdx.x;
    for (int i = bid * 256 + tid; i < kTok * kPROJ; i += 384 * 256)
      proj_zero[i] = 0.f;
  }
  for (int i = tid; i < kDM; i += 256) { sg_[i] = g[i]; sb_[i] = bb[i]; }
  // LN stats prepass: 4 threads per row
  {
    int r = tid >> 2, quarter = tid & 3;
    const float* rp = tok + (size_t)(bm + r) * kDM + quarter * 96;
    float s = 0.f, s2 = 0.f;
    #pragma unroll
    for (int q = 0; q < 24; ++q) {
      float4 v = ((const float4*)rp)[q];
      s  += v.x + v.y + v.z + v.w;
      s2 += v.x * v.x + v.y * v.y + v.z * v.z + v.w * v.w;
    }
    s  += __shfl_xor(s, 1);  s2 += __shfl_xor(s2, 1);
    s  += __shfl_xor(s, 2);  s2 += __shfl_xor(s2, 2);
    if (quarter == 0) {
      float mean = s * (1.f / 384.f);
      float var  = s2 * (1.f / 384.f) - mean * mean;
      smean[r] = mean;
      srstd[r] = rsqrtf(var + 1e-5f);
    }
  }
  __syncthreads();
  int wave = tid >> 6, lane = tid & 63;
  int lm = lane & 15, lq = lane >> 4;
  int wm = (wave & 1) * 32, wn = (wave >> 1) * 64;
  f32x4 acc[2][4] = {};
  for (int k0 = 0; k0 < kDM; k0 += 32) {
    int ar = tid & 63, aq = tid >> 6;  // aq 0..3 (k-quad)
    unsigned short av[8];
    {
      float mean = smean[ar], rstd = srstd[ar];
      const float* ap = tok + (size_t)(bm + ar) * kDM + k0 + aq * 8;
      float4 v0 = ((const float4*)ap)[0];
      float4 v1 = ((const float4*)ap)[1];
      float vv[8] = {v0.x, v0.y, v0.z, v0.w, v1.x, v1.y, v1.z, v1.w};
      #pragma unroll
      for (int j = 0; j < 8; ++j) {
        int k = k0 + aq * 8 + j;
        av[j] = f2bf((vv[j] - mean) * rstd * sg_[k] + sb_[k]);
      }
    }
    int br = tid & 127, bq0 = tid >> 7, bq1 = bq0 + 2;
    uint4 b0 = *(const uint4*)(Bw + (size_t)(bn + br) * kDM + k0 + bq0 * 8);
    uint4 b1 = *(const uint4*)(Bw + (size_t)(bn + br) * kDM + k0 + bq1 * 8);
    __syncthreads();
    *(uint4*)&As[aq][ar][0]  = *(const uint4*)av;
    *(uint4*)&Bs[bq0][br][0] = b0;
    *(uint4*)&Bs[bq1][br][0] = b1;
    __syncthreads();
    short8 bfrag[4];
    #pragma unroll
    for (int ni = 0; ni < 4; ++ni)
      bfrag[ni] = *(const short8*)&Bs[lq][wn + ni * 16 + lm][0];
    #pragma unroll
    for (int mi = 0; mi < 2; ++mi) {
      short8 afrag = *(const short8*)&As[lq][wm + mi * 16 + lm][0];
      #pragma unroll
      for (int ni = 0; ni < 4; ++ni)
        acc[mi][ni] = __builtin_amdgcn_mfma_f32_16x16x32_bf16(
            afrag, bfrag[ni], acc[mi][ni], 0, 0, 0);
    }
  }
  #pragma unroll
  for (int mi = 0; mi < 2; ++mi) {
    #pragma unroll
    for (int ni = 0; ni < 4; ++ni) {
      int grow0 = bm + wm + mi * 16 + lq * 4;
      int gcol = bn + wn + ni * 16 + lm;
      #pragma unroll
      for (int r = 0; r < 4; ++r)
        Cbf[(size_t)(grow0 + r) * (2 * kDI) + gcol] = f2bf(acc[mi][ni][r]);
    }
  }
}

// ------------- x_proj with fused depthwise conv + SiLU + z-gate ------------
// grid (32, 6) = 192 blocks. Side outputs: uT_bf[b][d][l] and
// sgT_bf[b][d][l] = silu(z) (both bf16, lane-contiguous along l).
__global__ __launch_bounds__(256) void xproj_conv_k(
    const unsigned short* __restrict__ xz, const unsigned short* __restrict__ Bw,
    const float* __restrict__ cw, const float* __restrict__ cb,
    float* __restrict__ proj, unsigned short* __restrict__ uT_bf,
    unsigned short* __restrict__ sgT_bf) {
  __shared__ __align__(16) unsigned short As[4][64][8];
  __shared__ __align__(16) unsigned short Bs[4][64][8];
  __shared__ float scw[128][4];
  __shared__ float scb[128];
  int tid = threadIdx.x;
  int bm = blockIdx.x * 64;       // token tile
  int kbase = blockIdx.y * 128;   // d chunk (split-K = 6)
  int wave = tid >> 6, lane = tid & 63;
  int lm = lane & 15, lq = lane >> 4;
  int wm = wave * 16;
  f32x4 acc[4] = {};

  if (tid < 128) {
    *(float4*)&scw[tid][0] = *(const float4*)(cw + (size_t)(kbase + tid) * 4);
    scb[tid] = cb[kbase + tid];
  }
  __syncthreads();

  int ar = tid & 63;
  int aq = tid >> 6;   // 0..3
  int t = bm + ar;
  int b = t >> 8, l = t & 255;

  for (int kt = 0; kt < 4; ++kt) {
    int k0 = kbase + kt * 32;
    int dloc = kt * 32 + aq * 8;
    int dg = kbase + dloc;
    unsigned short av[8];
    {
      float vals[4][8];
      #pragma unroll
      for (int q = 0; q < 4; ++q) {
        if (l - 3 + q >= 0) {
          uint4 r = *(const uint4*)(xz + (size_t)(t - 3 + q) * (2 * kDI) + dg);
          const unsigned short* rs = (const unsigned short*)&r;
          #pragma unroll
          for (int j = 0; j < 8; ++j) vals[q][j] = bf2f(rs[j]);
        } else {
          #pragma unroll
          for (int j = 0; j < 8; ++j) vals[q][j] = 0.f;
        }
      }
      // z-gate for the same 8 channels (row t, offset +768)
      uint4 zr = *(const uint4*)(xz + (size_t)t * (2 * kDI) + kDI + dg);
      const unsigned short* zs = (const unsigned short*)&zr;
      #pragma unroll
      for (int j = 0; j < 8; ++j) {
        float a = scb[dloc + j];
        a = fmaf(vals[0][j], scw[dloc + j][0], a);
        a = fmaf(vals[1][j], scw[dloc + j][1], a);
        a = fmaf(vals[2][j], scw[dloc + j][2], a);
        a = fmaf(vals[3][j], scw[dloc + j][3], a);
        unsigned short ub = f2bf(silu_f(a));
        av[j] = ub;
        size_t rbase = ((size_t)b * kDI + dg + j) * kL + l;
        uT_bf[rbase] = ub;
        sgT_bf[rbase] = f2bf(silu_f(bf2f(zs[j])));
      }
    }
    int br = tid & 63, bq = tid >> 6;
    uint4 b0;
    if (br < kPROJ)
      b0 = *(const uint4*)(Bw + (size_t)br * kDI + k0 + bq * 8);
    else
      b0 = make_uint4(0u, 0u, 0u, 0u);
    __syncthreads();
    *(uint4*)&As[aq][ar][0] = *(const uint4*)av;
    *(uint4*)&Bs[bq][br][0] = b0;
    __syncthreads();
    short8 afrag = *(const short8*)&As[lq][wm + lm][0];
    #pragma unroll
    for (int ni = 0; ni < 4; ++ni) {
      short8 bfrag = *(const short8*)&Bs[lq][ni * 16 + lm][0];
      acc[ni] = __builtin_amdgcn_mfma_f32_16x16x32_bf16(
          afrag, bfrag, acc[ni], 0, 0, 0);
    }
  }

  #pragma unroll
  for (int ni = 0; ni < 4; ++ni) {
    int grow0 = bm + wm + lq * 4;
    int gcol = ni * 16 + lm;
    if (gcol < kPROJ) {
      #pragma unroll
      for (int r = 0; r < 4; ++r)
        atomicAdd(&proj[(size_t)(grow0 + r) * kPROJ + gcol], acc[ni][r]);
    }
  }
}

// ------------- bf16 MFMA NT GEMM (out_proj): atomicAdd into residual -------
// 64x64 tiles: grid (6, 32, 4) = 768 blocks (3/CU). Wave = 32x32 quadrant.
__global__ __launch_bounds__(256) void bgemm_out_k(
    const unsigned short* __restrict__ A, int lda,
    const unsigned short* __restrict__ B, int ldb,
    float* __restrict__ C, int ldc, int Kc) {
  __shared__ __align__(16) unsigned short As[4][64][8];
  __shared__ __align__(16) unsigned short Bs[4][64][8];
  int tid = threadIdx.x;
  int bm = blockIdx.y * 64;
  int bn = blockIdx.x * 64;
  int k_begin = blockIdx.z * Kc;
  int wave = tid >> 6, lane = tid & 63;
  int lm = lane & 15, lq = lane >> 4;
  int wm = (wave & 1) * 32, wn = (wave >> 1) * 32;
  f32x4 acc[2][2] = {};

  for (int kt = 0; kt < Kc; kt += 32) {
    int k0 = k_begin + kt;
    int ar = tid & 63, aq = tid >> 6;
    uint4 a0 = *(const uint4*)(A + (size_t)(bm + ar) * lda + k0 + aq * 8);
    uint4 b0 = *(const uint4*)(B + (size_t)(bn + ar) * ldb + k0 + aq * 8);
    __syncthreads();
    *(uint4*)&As[aq][ar][0] = a0;
    *(uint4*)&Bs[aq][ar][0] = b0;
    __syncthreads();
    short8 bfrag[2];
    #pragma unroll
    for (int ni = 0; ni < 2; ++ni)
      bfrag[ni] = *(const short8*)&Bs[lq][wn + ni * 16 + lm][0];
    #pragma unroll
    for (int mi = 0; mi < 2; ++mi) {
      short8 afrag = *(const short8*)&As[lq][wm + mi * 16 + lm][0];
      #pragma unroll
      for (int ni = 0; ni < 2; ++ni)
        acc[mi][ni] = __builtin_amdgcn_mfma_f32_16x16x32_bf16(
            afrag, bfrag[ni], acc[mi][ni], 0, 0, 0);
    }
  }

  #pragma unroll
  for (int mi = 0; mi < 2; ++mi) {
    #pragma unroll
    for (int ni = 0; ni < 2; ++ni) {
      int grow0 = bm + wm + mi * 16 + lq * 4;
      int gcol = bn + wn + ni * 16 + lm;
      #pragma unroll
      for (int r = 0; r < 4; ++r)
        atomicAdd(&C[(size_t)(grow0 + r) * ldc + gcol], acc[mi][ni][r]);
    }
  }
}

// ------------- split-state register scan + fused dt_proj (v2, r1-best) -----
// thread = (chunk c[16], state-quarter nq[4], dsub[4]); 4 SSM states/thread,
// 4 d-channels/block, grid (192, 8) = 1536 blocks. Direct global proj reads
// (r1 measured this ≤42µs vs 56µs for the 48KB-LDS staged v3 — occupancy
// beats staging here). dt in LDS; u and silu(z) packed bf16.
__global__ __launch_bounds__(256, 5) void scansplit_k(
    const float* __restrict__ proj, const unsigned short* __restrict__ uT_bf,
    const unsigned short* __restrict__ sgT_bf, const float* __restrict__ dtw,
    const float* __restrict__ dtb, const float* __restrict__ A_log,
    const float* __restrict__ Dsk, unsigned short* __restrict__ y_bf) {
  int d0 = blockIdx.x * 4;
  int b = blockIdx.y;
  int tid = threadIdx.x;
  int dsub = tid & 3;
  int nq = (tid >> 2) & 3;   // state quarter: states nq*4 .. nq*4+3
  int c = tid >> 4;          // chunk of 16 tokens
  int d = d0 + dsub;
  __shared__ float sdt[16][16][5];   // [chunk][token-in-chunk][dsub]
  __shared__ float sh[16][16][5];    // [chunk][state][dsub]
  __shared__ float sca[16][16][5];

  // A (pre-scaled by log2(e) so the scan uses exp2 directly)
  float Av2[4];
  {
    const float kLog2e = 1.44269504088896340736f;
    float4 v = *(const float4*)(A_log + (size_t)d * kDS + nq * 4);
    Av2[0] = -__expf(v.x) * kLog2e;
    Av2[1] = -__expf(v.y) * kLog2e;
    Av2[2] = -__expf(v.z) * kLog2e;
    Av2[3] = -__expf(v.w) * kLog2e;
  }
  float bdt = dtb[d];
  float Dv = Dsk[d];

  const float* pr = proj + ((size_t)(b * kL) + c * 16) * kPROJ;

  // dt_proj for my 4 tokens (l = c*16 + nq*4 + i) -> sdt
  {
    float wdt[24];
    const float* wp = dtw + (size_t)d * kDTR;
    #pragma unroll
    for (int q = 0; q < 6; ++q) {
      float4 v = ((const float4*)wp)[q];
      wdt[q * 4 + 0] = v.x; wdt[q * 4 + 1] = v.y;
      wdt[q * 4 + 2] = v.z; wdt[q * 4 + 3] = v.w;
    }
    #pragma unroll
    for (int i = 0; i < 4; ++i) {
      const float* p = pr + (size_t)(nq * 4 + i) * kPROJ;
      float acc = bdt;
      #pragma unroll
      for (int q = 0; q < 6; ++q) {
        float4 v = ((const float4*)p)[q];
        acc = fmaf(v.x, wdt[q * 4 + 0], acc);
        acc = fmaf(v.y, wdt[q * 4 + 1], acc);
        acc = fmaf(v.z, wdt[q * 4 + 2], acc);
        acc = fmaf(v.w, wdt[q * 4 + 3], acc);
      }
      sdt[c][nq * 4 + i][dsub] = softplus_f(acc);
    }
  }

  // u: 16 bf16 tokens packed in 2 uint4 (8 VGPRs), unpacked per use
  union { uint4 v[2]; unsigned short s[16]; } uu;
  {
    const unsigned short* up = uT_bf + ((size_t)b * kDI + d) * kL + c * 16;
    uu.v[0] = ((const uint4*)up)[0];
    uu.v[1] = ((const uint4*)up)[1];
  }
  __syncthreads();

  // pass 1: local chunk scan over my 4 states
  float h[4] = {}, ca[4] = {1.f, 1.f, 1.f, 1.f};
  #pragma unroll
  for (int i = 0; i < 16; ++i) {
    float dl = sdt[c][i][dsub];
    float du = dl * bf2f(uu.s[i]);
    float4 Bq = *(const float4*)(pr + (size_t)i * kPROJ + 24 + nq * 4);
    float Bv[4] = {Bq.x, Bq.y, Bq.z, Bq.w};
    #pragma unroll
    for (int n = 0; n < 4; ++n) {
      float a = exp2f(dl * Av2[n]);
      h[n] = fmaf(a, h[n], du * Bv[n]);
      ca[n] *= a;
    }
  }
  {
    int nrow = nq * 4;
    #pragma unroll
    for (int n = 0; n < 4; ++n) {
      sh[c][nrow + n][dsub] = h[n];
      sca[c][nrow + n][dsub] = ca[n];
    }
  }
  __syncthreads();

  // chunk-prefix combine (same address across the wave -> LDS broadcast)
  float h0[4] = {};
  {
    int nrow = nq * 4;
    for (int j = 0; j < c; ++j) {
      #pragma unroll
      for (int n = 0; n < 4; ++n)
        h0[n] = fmaf(sca[j][nrow + n][dsub], h0[n], sh[j][nrow + n][dsub]);
    }
  }

  // z-gate for nq==0 quarter: packed bf16 (8 VGPRs)
  union { uint4 v[2]; unsigned short s[16]; } zz;
  zz.v[0] = make_uint4(0u, 0u, 0u, 0u);
  zz.v[1] = make_uint4(0u, 0u, 0u, 0u);
  if (nq == 0) {
    const unsigned short* sp = sgT_bf + ((size_t)b * kDI + d) * kL + c * 16;
    zz.v[0] = ((const uint4*)sp)[0];
    zz.v[1] = ((const uint4*)sp)[1];
  }

  // pass 2: true scan from h0; partial y over my 4 states; 2 shuffles; store
  unsigned short* yp = y_bf + (size_t)(b * kL + c * 16) * kDI + d;
  #pragma unroll
  for (int i = 0; i < 16; ++i) {
    float dl = sdt[c][i][dsub];
    float uv = bf2f(uu.s[i]);
    float du = dl * uv;
    const float* p = pr + (size_t)i * kPROJ + 24 + nq * 4;
    float4 Bq = *(const float4*)p;
    float4 Cq = *(const float4*)(p + 16);
    float Bv[4] = {Bq.x, Bq.y, Bq.z, Bq.w};
    float Cv[4] = {Cq.x, Cq.y, Cq.z, Cq.w};
    float yv = 0.f;
    #pragma unroll
    for (int n = 0; n < 4; ++n) {
      float a = exp2f(dl * Av2[n]);
      h0[n] = fmaf(a, h0[n], du * Bv[n]);
      yv = fmaf(h0[n], Cv[n], yv);
    }
    yv += __shfl_xor(yv, 4);
    yv += __shfl_xor(yv, 8);
    if (nq == 0) yp[(size_t)i * kDI] = f2bf((yv + uv * Dv) * bf2f(zz.s[i]));
  }
}

}  // namespace

extern "C" void kernel_launch(void* const* d_in, const int* in_sizes, int n_in,
                              void* d_out, int out_size, void* d_ws, size_t ws_size,
                              hipStream_t stream) {
  (void)in_sizes; (void)n_in; (void)out_size; (void)ws_size;
  const float* x        = (const float*)d_in[0];
  const float* patch_w  = (const float*)d_in[1];
  const float* patch_b  = (const float*)d_in[2];
  const float* pos      = (const float*)d_in[3];
  const float* ln_g     = (const float*)d_in[4];
  const float* ln_b     = (const float*)d_in[5];
  const float* in_w     = (const float*)d_in[6];
  const float* conv_w   = (const float*)d_in[7];
  const float* conv_b   = (const float*)d_in[8];
  const float* xproj_w  = (const float*)d_in[9];
  const float* dtproj_w = (const float*)d_in[10];
  const float* dtproj_b = (const float*)d_in[11];
  const float* A_log    = (const float*)d_in[12];
  const float* Dskip    = (const float*)d_in[13];
  const float* out_w    = (const float*)d_in[14];
  const float* fn_g     = (const float*)d_in[15];
  const float* fn_b     = (const float*)d_in[16];
  const float* head_w   = (const float*)d_in[17];
  const float* head_b   = (const float*)d_in[18];
  float* out = (float*)d_out;

  float* ws = (float*)d_ws;
  float* tok    = ws; ws += kTok * kDM;       // fp32 residual
  float* proj   = ws; ws += kTok * kPROJ;     // [t][56] row-major
  unsigned short* xz_bf  = (unsigned short*)ws; ws += kTok * 2 * kDI / 2;
  unsigned short* uT_bf  = (unsigned short*)ws; ws += kTok * kDI / 2;
  unsigned short* sgT_bf = (unsigned short*)ws; ws += kTok * kDI / 2;
  unsigned short* y_bf   = (unsigned short*)ws; ws += kTok * kDI / 2;
  unsigned short* w_bf   = (unsigned short*)ws; ws += (size_t)kNL * kWTOT / 2;

  // all-layer weight cast (once per call)
  convert_all_k<<<dim3(kWTOT / 4 / 256, kNL), 256, 0, stream>>>(
      in_w, out_w, xproj_w, w_bf);

  // Patch embedding fused: im2col + GEMM + bias + pos
  patch_gemm_k<<<dim3(6, 32), 256, 0, stream>>>(x, patch_w, patch_b, pos, tok);

  for (int layer = 0; layer < kNL; ++layer) {
    const unsigned short* wl = w_bf + (size_t)layer * kWTOT;
    // in_proj with fused LN (+ proj zero): LN(tok) x W^T -> xz_bf  (384 blk)
    inproj_ln_k<<<dim3(12, 32), 256, 0, stream>>>(
        tok, wl, ln_g + layer * kDM, ln_b + layer * kDM, xz_bf, proj);
    // x_proj with fused conv+SiLU+z-gate: proj += u·Wx^T ; uT_bf, sgT_bf
    xproj_conv_k<<<dim3(32, 6), 256, 0, stream>>>(
        xz_bf, wl + kWIN + kWOUT, conv_w + layer * kDI * 4,
        conv_b + layer * kDI, proj, uT_bf, sgT_bf);
    // split-state register scan v2 + fused dt_proj -> y_bf (1536 blk)
    scansplit_k<<<dim3(kDI / 4, kB), 256, 0, stream>>>(
        proj, uT_bf, sgT_bf, dtproj_w + (size_t)layer * kDI * kDTR,
        dtproj_b + layer * kDI, A_log + (size_t)layer * kDI * kDS,
        Dskip + layer * kDI, y_bf);
    // out_proj (MFMA, 64x64 tiles, split-K=4, atomic into residual)
    bgemm_out_k<<<dim3(6, 32, 4), 256, 0, stream>>>(
        y_bf, kDI, wl + kWIN, kDI, tok, kDM, kDI / 4);
  }

  // final LN + mean-pool + head fused (atomicAdd into harness-zeroed out)
  lnpool_head_k<<<kTok, kDM, 0, stream>>>(tok, fn_g, fn_b, head_w, head_b, out);
}